// Round 1
// baseline (1001.083 us; speedup 1.0000x reference)
//
#include <hip/hip_runtime.h>
#include <math.h>

#define NNODES 50000
#define NEDGES 800000

__device__ __forceinline__ float leaky(float x) { return x > 0.f ? x : 0.2f * x; }

// ---------------- CSR build ----------------
__global__ void hist_kernel(const int* __restrict__ dst, int* __restrict__ counts) {
    int e = blockIdx.x * 256 + threadIdx.x;
    if (e < NEDGES) atomicAdd(&counts[dst[e]], 1);
}

__global__ __launch_bounds__(1024) void scan_kernel(const int* __restrict__ counts,
                                                    int* __restrict__ row_start, int Nn) {
    __shared__ int sd[1024];
    int tid = threadIdx.x;
    int carry = 0;
    for (int base = 0; base < Nn; base += 1024) {
        int v = (base + tid < Nn) ? counts[base + tid] : 0;
        __syncthreads();            // protect prev-iter readers of sd
        sd[tid] = v;
        __syncthreads();
        for (int off = 1; off < 1024; off <<= 1) {
            int t = (tid >= off) ? sd[tid - off] : 0;
            __syncthreads();
            sd[tid] += t;
            __syncthreads();
        }
        int incl = sd[tid];
        if (base + tid < Nn) row_start[base + tid] = carry + incl - v;  // exclusive
        carry += sd[1023];
    }
    if (tid == 0) row_start[Nn] = carry;
}

__global__ void scatter_kernel(const int* __restrict__ src, const int* __restrict__ dst,
                               const int* __restrict__ row_start, int* __restrict__ cursor,
                               int* __restrict__ csr_src) {
    int e = blockIdx.x * 256 + threadIdx.x;
    if (e < NEDGES) {
        int d = dst[e];
        int pos = row_start[d] + atomicAdd(&cursor[d], 1);
        csr_src[pos] = src[e];
    }
}

// ---------------- pack [W2 | res_w2] into 256x128 ----------------
__global__ void pack_kernel(const float* __restrict__ W2, const float* __restrict__ Wr,
                            float* __restrict__ Wcat) {
    int idx = blockIdx.x * 256 + threadIdx.x;   // 0..32767
    int k = idx >> 7, c = idx & 127;
    Wcat[idx] = (c < 64) ? W2[k * 64 + c] : Wr[k * 64 + (c - 64)];
}

// ---------------- GEMM: C[N,M] = A[N,256] @ B[256,M] ----------------
template <int MCOLS>
__global__ __launch_bounds__(256) void gemm_kernel(const float* __restrict__ A,
                                                   const float* __restrict__ B,
                                                   float* __restrict__ C, int Nrows) {
    constexpr int K = 256, BK = 32, BM = 64;
    constexpr int AS = BK + 4;  // stride 36: keeps 16B align, <=2-way bank conflict (free)
    __shared__ float As[BM * AS];
    __shared__ float Bs[BK * MCOLS];
    const int tid = threadIdx.x;
    const int tx = tid & 15, ty = tid >> 4;
    const int row0 = blockIdx.x * BM;
    constexpr int CPT = MCOLS / 16;   // cols per thread
    float acc[4][CPT];
#pragma unroll
    for (int i = 0; i < 4; ++i)
#pragma unroll
        for (int j = 0; j < CPT; ++j) acc[i][j] = 0.f;

    for (int kk = 0; kk < K; kk += BK) {
        // A tile: 64 x 32 = 512 float4, 2 per thread
#pragma unroll
        for (int l = 0; l < 2; ++l) {
            int idx = tid + l * 256;
            int r = idx >> 3, q = idx & 7;
            float4 v = make_float4(0.f, 0.f, 0.f, 0.f);
            int gr = row0 + r;
            if (gr < Nrows) v = *reinterpret_cast<const float4*>(A + (size_t)gr * K + kk + q * 4);
            *reinterpret_cast<float4*>(&As[r * AS + q * 4]) = v;
        }
        // B tile: 32 x MCOLS
        constexpr int BL = (BK * MCOLS) / (4 * 256);
#pragma unroll
        for (int l = 0; l < BL; ++l) {
            int idx = tid + l * 256;
            int r = idx / (MCOLS / 4), c4 = idx % (MCOLS / 4);
            float4 v = *reinterpret_cast<const float4*>(B + (size_t)(kk + r) * MCOLS + c4 * 4);
            *reinterpret_cast<float4*>(&Bs[r * MCOLS + c4 * 4]) = v;
        }
        __syncthreads();
#pragma unroll 8
        for (int k = 0; k < BK; ++k) {
            float a0 = As[(ty * 4 + 0) * AS + k];
            float a1 = As[(ty * 4 + 1) * AS + k];
            float a2 = As[(ty * 4 + 2) * AS + k];
            float a3 = As[(ty * 4 + 3) * AS + k];
            float b[CPT];
#pragma unroll
            for (int j = 0; j < CPT; ++j) b[j] = Bs[k * MCOLS + j * 16 + tx];
#pragma unroll
            for (int j = 0; j < CPT; ++j) {
                acc[0][j] = fmaf(a0, b[j], acc[0][j]);
                acc[1][j] = fmaf(a1, b[j], acc[1][j]);
                acc[2][j] = fmaf(a2, b[j], acc[2][j]);
                acc[3][j] = fmaf(a3, b[j], acc[3][j]);
            }
        }
        __syncthreads();
    }
#pragma unroll
    for (int i = 0; i < 4; ++i) {
        int gr = row0 + ty * 4 + i;
        if (gr < Nrows) {
#pragma unroll
            for (int j = 0; j < CPT; ++j) C[(size_t)gr * MCOLS + j * 16 + tx] = acc[i][j];
        }
    }
}

// ---------------- el/er: per-node attention dot products ----------------
template <int H>
__global__ __launch_bounds__(256) void elr_kernel(const float* __restrict__ feat, int fstride,
                                                  const float* __restrict__ al,
                                                  const float* __restrict__ ar,
                                                  float* __restrict__ el, float* __restrict__ er,
                                                  int Nn) {
    int node = blockIdx.x * 4 + (threadIdx.x >> 6);
    int lane = threadIdx.x & 63;
    if (node >= Nn) return;
#pragma unroll
    for (int h = 0; h < H; ++h) {
        float f = feat[(size_t)node * fstride + h * 64 + lane];
        float sl = f * al[h * 64 + lane];
        float sr = f * ar[h * 64 + lane];
        for (int o = 32; o; o >>= 1) {
            sl += __shfl_xor(sl, o);
            sr += __shfl_xor(sr, o);
        }
        if (lane == 0) {
            el[node * H + h] = sl;
            er[node * H + h] = sr;
        }
    }
}

// ---------------- per-dst-node softmax aggregation (one wave per node) ----------------
// RES: 0 none, 1 identity (resbuf stride rstride, H*64 wide), 2 linear (resbuf stride rstride, 64 wide)
template <int H, int RES, bool ACT>
__global__ __launch_bounds__(256) void agg_kernel(
    const float* __restrict__ feat, int fstride, const float* __restrict__ el,
    const float* __restrict__ er, const int* __restrict__ row_start,
    const int* __restrict__ csr_src, const float* __restrict__ resbuf, int rstride,
    const float* __restrict__ bias, float* __restrict__ out, int ostride, int Nn) {
    int node = blockIdx.x * 4 + (threadIdx.x >> 6);
    int lane = threadIdx.x & 63;
    if (node >= Nn) return;

    int begin = row_start[node], end = row_start[node + 1];

    float ern[H];
#pragma unroll
    for (int h = 0; h < H; ++h) ern[h] = er[node * H + h];

    // pass 1: per-head max over incoming edges (lanes parallelize edges)
    float m[H];
#pragma unroll
    for (int h = 0; h < H; ++h) m[h] = -INFINITY;
    for (int i = begin + lane; i < end; i += 64) {
        int s = csr_src[i];
        if constexpr (H == 4) {
            float4 e4 = *(reinterpret_cast<const float4*>(el) + s);
            m[0] = fmaxf(m[0], leaky(e4.x + ern[0]));
            m[1] = fmaxf(m[1], leaky(e4.y + ern[1]));
            m[2] = fmaxf(m[2], leaky(e4.z + ern[2]));
            m[3] = fmaxf(m[3], leaky(e4.w + ern[3]));
        } else {
            m[0] = fmaxf(m[0], leaky(el[s] + ern[0]));
        }
    }
#pragma unroll
    for (int h = 0; h < H; ++h)
        for (int o = 32; o; o >>= 1) m[h] = fmaxf(m[h], __shfl_xor(m[h], o));

    // pass 2: weighted accumulate (lane = feature dim)
    float denom[H], acc[H];
#pragma unroll
    for (int h = 0; h < H; ++h) { denom[h] = 0.f; acc[h] = 0.f; }
    for (int i = begin; i < end; ++i) {
        int s = csr_src[i];
        const float* fr = feat + (size_t)s * fstride + lane;
        if constexpr (H == 4) {
            float4 e4 = *(reinterpret_cast<const float4*>(el) + s);
            float w0 = __expf(leaky(e4.x + ern[0]) - m[0]);
            float w1 = __expf(leaky(e4.y + ern[1]) - m[1]);
            float w2 = __expf(leaky(e4.z + ern[2]) - m[2]);
            float w3 = __expf(leaky(e4.w + ern[3]) - m[3]);
            denom[0] += w0; denom[1] += w1; denom[2] += w2; denom[3] += w3;
            acc[0] = fmaf(w0, fr[0], acc[0]);
            acc[1] = fmaf(w1, fr[64], acc[1]);
            acc[2] = fmaf(w2, fr[128], acc[2]);
            acc[3] = fmaf(w3, fr[192], acc[3]);
        } else {
            float w = __expf(leaky(el[s] + ern[0]) - m[0]);
            denom[0] += w;
            acc[0] = fmaf(w, fr[0], acc[0]);
        }
    }

#pragma unroll
    for (int h = 0; h < H; ++h) {
        float o = (end > begin) ? acc[h] / denom[h] : 0.f;
        if constexpr (RES == 1) o += resbuf[(size_t)node * rstride + h * 64 + lane];
        if constexpr (RES == 2) o += resbuf[(size_t)node * rstride + lane];
        o += bias[h * 64 + lane];
        if constexpr (ACT) o = (o > 0.f) ? o : (__expf(o) - 1.f);
        out[(size_t)node * ostride + h * 64 + lane] = o;
    }
}

// ---------------- launch ----------------
extern "C" void kernel_launch(void* const* d_in, const int* in_sizes, int n_in, void* d_out,
                              int out_size, void* d_ws, size_t ws_size, hipStream_t stream) {
    const float* x   = (const float*)d_in[0];
    const int* src   = (const int*)d_in[1];
    const int* dst   = (const int*)d_in[2];
    const float* W0  = (const float*)d_in[3];
    const float* al0 = (const float*)d_in[4];
    const float* ar0 = (const float*)d_in[5];
    const float* b0  = (const float*)d_in[6];
    const float* W1  = (const float*)d_in[7];
    const float* al1 = (const float*)d_in[8];
    const float* ar1 = (const float*)d_in[9];
    const float* b1  = (const float*)d_in[10];
    const float* W2  = (const float*)d_in[11];
    const float* al2 = (const float*)d_in[12];
    const float* ar2 = (const float*)d_in[13];
    const float* b2  = (const float*)d_in[14];
    const float* Wr2 = (const float*)d_in[15];
    float* out = (float*)d_out;

    char* w = (char*)d_ws;
    size_t off = 0;
    auto alloc = [&](size_t bytes) -> char* {
        char* p = w + off;
        off += (bytes + 255) & ~(size_t)255;
        return p;
    };
    float* feat      = (float*)alloc((size_t)NNODES * 256 * 4);
    float* hbuf      = (float*)alloc((size_t)NNODES * 256 * 4);
    float* el        = (float*)alloc((size_t)NNODES * 4 * 4);
    float* er        = (float*)alloc((size_t)NNODES * 4 * 4);
    float* Wcat      = (float*)alloc(256 * 128 * 4);
    int* counts      = (int*)alloc((size_t)NNODES * 4);
    int* cursor      = (int*)alloc((size_t)NNODES * 4);
    int* row_start   = (int*)alloc((size_t)(NNODES + 1) * 4);
    int* csr_src     = (int*)alloc((size_t)NEDGES * 4);

    hipMemsetAsync(counts, 0, (size_t)NNODES * 4, stream);
    hipMemsetAsync(cursor, 0, (size_t)NNODES * 4, stream);

    const int EB = (NEDGES + 255) / 256;
    const int NB64 = (NNODES + 63) / 64;
    const int NB4 = (NNODES + 3) / 4;

    hist_kernel<<<EB, 256, 0, stream>>>(dst, counts);
    scan_kernel<<<1, 1024, 0, stream>>>(counts, row_start, NNODES);
    scatter_kernel<<<EB, 256, 0, stream>>>(src, dst, row_start, cursor, csr_src);
    pack_kernel<<<128, 256, 0, stream>>>(W2, Wr2, Wcat);

    // ---- layer 0: x -> feat -> hbuf (ELU, no residual)
    gemm_kernel<256><<<NB64, 256, 0, stream>>>(x, W0, feat, NNODES);
    elr_kernel<4><<<NB4, 256, 0, stream>>>(feat, 256, al0, ar0, el, er, NNODES);
    agg_kernel<4, 0, true><<<NB4, 256, 0, stream>>>(feat, 256, el, er, row_start, csr_src,
                                                    nullptr, 0, b0, hbuf, 256, NNODES);
    // ---- layer 1: hbuf -> feat -> hbuf (ELU, identity residual; in-place safe:
    //      residual read at node n happens before out write at node n, feat is separate)
    gemm_kernel<256><<<NB64, 256, 0, stream>>>(hbuf, W1, feat, NNODES);
    elr_kernel<4><<<NB4, 256, 0, stream>>>(feat, 256, al1, ar1, el, er, NNODES);
    agg_kernel<4, 1, true><<<NB4, 256, 0, stream>>>(feat, 256, el, er, row_start, csr_src,
                                                    hbuf, 256, b1, hbuf, 256, NNODES);
    // ---- layer 2: hbuf @ [W2|res_w2] -> feat[N,128]; head feat = cols 0..63, linear
    //      residual = cols 64..127; output -> d_out (no activation)
    gemm_kernel<128><<<NB64, 256, 0, stream>>>(hbuf, Wcat, feat, NNODES);
    elr_kernel<1><<<NB4, 256, 0, stream>>>(feat, 128, al2, ar2, el, er, NNODES);
    agg_kernel<1, 2, false><<<NB4, 256, 0, stream>>>(feat, 128, el, er, row_start, csr_src,
                                                     feat + 64, 128, b2, out, 64, NNODES);
}

// Round 2
// 763.453 us; speedup vs baseline: 1.3113x; 1.3113x over previous
//
#include <hip/hip_runtime.h>
#include <math.h>

#define NNODES 50000
#define NEDGES 800000

__device__ __forceinline__ float leaky(float x) { return x > 0.f ? x : 0.2f * x; }

__device__ __forceinline__ ushort f2bf(float f) {
    unsigned u = __float_as_uint(f);
    return (ushort)((u + 0x7fffu + ((u >> 16) & 1u)) >> 16);  // RNE
}

// ---------------- CSR build ----------------
__global__ void hist_kernel(const int* __restrict__ dst, int* __restrict__ counts) {
    int e = blockIdx.x * 256 + threadIdx.x;
    if (e < NEDGES) atomicAdd(&counts[dst[e]], 1);
}

__global__ __launch_bounds__(1024) void scan_kernel(const int* __restrict__ counts,
                                                    int* __restrict__ row_start, int Nn) {
    __shared__ int sd[1024];
    int tid = threadIdx.x;
    int carry = 0;
    for (int base = 0; base < Nn; base += 1024) {
        int v = (base + tid < Nn) ? counts[base + tid] : 0;
        __syncthreads();
        sd[tid] = v;
        __syncthreads();
        for (int off = 1; off < 1024; off <<= 1) {
            int t = (tid >= off) ? sd[tid - off] : 0;
            __syncthreads();
            sd[tid] += t;
            __syncthreads();
        }
        int incl = sd[tid];
        if (base + tid < Nn) row_start[base + tid] = carry + incl - v;
        carry += sd[1023];
    }
    if (tid == 0) row_start[Nn] = carry;
}

__global__ void scatter_kernel(const int* __restrict__ src, const int* __restrict__ dst,
                               const int* __restrict__ row_start, int* __restrict__ cursor,
                               int* __restrict__ csr_src) {
    int e = blockIdx.x * 256 + threadIdx.x;
    if (e < NEDGES) {
        int d = dst[e];
        int pos = row_start[d] + atomicAdd(&cursor[d], 1);
        csr_src[pos] = src[e];
    }
}

// ---------------- pack weights: Bt[n][k] bf16 (transposed + converted) ----------------
__global__ void pack_kernel(const float* __restrict__ W0, const float* __restrict__ W1,
                            const float* __restrict__ W2, const float* __restrict__ Wr,
                            ushort* __restrict__ Bt0, ushort* __restrict__ Bt1,
                            ushort* __restrict__ Bt2) {
    int idx = blockIdx.x * 256 + threadIdx.x;  // 0..163839
    if (idx < 65536) {
        int n = idx >> 8, k = idx & 255;
        Bt0[idx] = f2bf(W0[k * 256 + n]);
    } else if (idx < 131072) {
        int j = idx - 65536;
        int n = j >> 8, k = j & 255;
        Bt1[j] = f2bf(W1[k * 256 + n]);
    } else {
        int j = idx - 131072;
        int n = j >> 8, k = j & 255;
        Bt2[j] = f2bf(n < 64 ? W2[k * 64 + n] : Wr[k * 64 + (n - 64)]);
    }
}

// ---------------- MFMA GEMM: C[N,MCOLS] = A[N,256](f32) @ Bt[MCOLS,256]^T(bf16) ----------------
// 128x128 block tile, 4 waves in 2x2, each 64x64 via 16x16x32 bf16 MFMA.
// LDS fragment-ordered: chunk(mf,kg,mr) at ((mf*8+kg)*16 + (mr^kg))*8 ushorts (kg-XOR swizzle).
template <int MCOLS>
__global__ __launch_bounds__(256) void gemm_mfma(const float* __restrict__ A,
                                                 const ushort* __restrict__ Bt,
                                                 float* __restrict__ C, int Nrows) {
    using bf16x8 = __attribute__((ext_vector_type(8))) short;
    using f32x4 = __attribute__((ext_vector_type(4))) float;
    __shared__ ushort As[8192];  // 128 rows x 64 k, bf16
    __shared__ ushort Bs[8192];
    const int tid = threadIdx.x;
    const int lane = tid & 63;
    const int wave = tid >> 6;
    const int wr = wave >> 1, wc = wave & 1;
    const int q = lane >> 4, li = lane & 15;
    const int r0 = blockIdx.x * 128;
    const int n0 = blockIdx.y * 128;

    f32x4 acc[4][4];
#pragma unroll
    for (int i = 0; i < 4; ++i)
#pragma unroll
        for (int j = 0; j < 4; ++j) acc[i][j] = (f32x4){0.f, 0.f, 0.f, 0.f};

    for (int kk = 0; kk < 256; kk += 64) {
        __syncthreads();
        // stage A (fp32 -> bf16 convert)
#pragma unroll
        for (int j = 0; j < 4; ++j) {
            int g = j * 256 + tid;
            int m = g >> 3, kg = g & 7;
            int mf = m >> 4, mr = m & 15;
            int row = r0 + m;
            float4 v0 = make_float4(0.f, 0.f, 0.f, 0.f), v1 = v0;
            if (row < Nrows) {
                const float* p = A + (size_t)row * 256 + kk + kg * 8;
                v0 = *reinterpret_cast<const float4*>(p);
                v1 = *reinterpret_cast<const float4*>(p + 4);
            }
            union { bf16x8 v; ushort u[8]; } pk;
            pk.u[0] = f2bf(v0.x); pk.u[1] = f2bf(v0.y);
            pk.u[2] = f2bf(v0.z); pk.u[3] = f2bf(v0.w);
            pk.u[4] = f2bf(v1.x); pk.u[5] = f2bf(v1.y);
            pk.u[6] = f2bf(v1.z); pk.u[7] = f2bf(v1.w);
            *reinterpret_cast<bf16x8*>(&As[((mf * 8 + kg) * 16 + (mr ^ kg)) * 8]) = pk.v;
        }
        // stage B (already bf16)
#pragma unroll
        for (int j = 0; j < 4; ++j) {
            int g = j * 256 + tid;
            int n = g >> 3, kg = g & 7;
            int nf = n >> 4, nr = n & 15;
            bf16x8 v = *reinterpret_cast<const bf16x8*>(Bt + (size_t)(n0 + n) * 256 + kk + kg * 8);
            *reinterpret_cast<bf16x8*>(&Bs[((nf * 8 + kg) * 16 + (nr ^ kg)) * 8]) = v;
        }
        __syncthreads();
#pragma unroll
        for (int t = 0; t < 2; ++t) {
            const int kc = t * 4 + q;
            bf16x8 af[4], bfv[4];
#pragma unroll
            for (int f = 0; f < 4; ++f) {
                af[f] = *reinterpret_cast<const bf16x8*>(
                    &As[(((wr * 4 + f) * 8 + kc) * 16 + (li ^ kc)) * 8]);
                bfv[f] = *reinterpret_cast<const bf16x8*>(
                    &Bs[(((wc * 4 + f) * 8 + kc) * 16 + (li ^ kc)) * 8]);
            }
#pragma unroll
            for (int f = 0; f < 4; ++f)
#pragma unroll
                for (int f2 = 0; f2 < 4; ++f2)
                    acc[f][f2] =
                        __builtin_amdgcn_mfma_f32_16x16x32_bf16(af[f], bfv[f2], acc[f][f2], 0, 0, 0);
        }
    }
    // epilogue: D[m][n], m = wr*64+f*16+q*4+r, n = wc*64+f2*16+li
#pragma unroll
    for (int f = 0; f < 4; ++f) {
#pragma unroll
        for (int r = 0; r < 4; ++r) {
            int row = r0 + wr * 64 + f * 16 + q * 4 + r;
            if (row < Nrows) {
#pragma unroll
                for (int f2 = 0; f2 < 4; ++f2)
                    C[(size_t)row * MCOLS + n0 + wc * 64 + f2 * 16 + li] = acc[f][f2][r];
            }
        }
    }
}

// ---------------- el/er: per-node attention dot products ----------------
template <int H>
__global__ __launch_bounds__(256) void elr_kernel(const float* __restrict__ feat, int fstride,
                                                  const float* __restrict__ al,
                                                  const float* __restrict__ ar,
                                                  float* __restrict__ el, float* __restrict__ er,
                                                  int Nn) {
    int node = blockIdx.x * 4 + (threadIdx.x >> 6);
    int lane = threadIdx.x & 63;
    if (node >= Nn) return;
#pragma unroll
    for (int h = 0; h < H; ++h) {
        float f = feat[(size_t)node * fstride + h * 64 + lane];
        float sl = f * al[h * 64 + lane];
        float sr = f * ar[h * 64 + lane];
        for (int o = 32; o; o >>= 1) {
            sl += __shfl_xor(sl, o);
            sr += __shfl_xor(sr, o);
        }
        if (lane == 0) {
            el[node * H + h] = sl;
            er[node * H + h] = sr;
        }
    }
}

// ---------------- per-dst-node softmax aggregation (one wave per node) ----------------
template <int H, int RES, bool ACT>
__global__ __launch_bounds__(256) void agg_kernel(
    const float* __restrict__ feat, int fstride, const float* __restrict__ el,
    const float* __restrict__ er, const int* __restrict__ row_start,
    const int* __restrict__ csr_src, const float* __restrict__ resbuf, int rstride,
    const float* __restrict__ bias, float* __restrict__ out, int ostride, int Nn) {
    int node = blockIdx.x * 4 + (threadIdx.x >> 6);
    int lane = threadIdx.x & 63;
    if (node >= Nn) return;

    int begin = row_start[node], end = row_start[node + 1];

    float ern[H];
#pragma unroll
    for (int h = 0; h < H; ++h) ern[h] = er[node * H + h];

    float m[H];
#pragma unroll
    for (int h = 0; h < H; ++h) m[h] = -INFINITY;
    for (int i = begin + lane; i < end; i += 64) {
        int s = csr_src[i];
        if constexpr (H == 4) {
            float4 e4 = *(reinterpret_cast<const float4*>(el) + s);
            m[0] = fmaxf(m[0], leaky(e4.x + ern[0]));
            m[1] = fmaxf(m[1], leaky(e4.y + ern[1]));
            m[2] = fmaxf(m[2], leaky(e4.z + ern[2]));
            m[3] = fmaxf(m[3], leaky(e4.w + ern[3]));
        } else {
            m[0] = fmaxf(m[0], leaky(el[s] + ern[0]));
        }
    }
#pragma unroll
    for (int h = 0; h < H; ++h)
        for (int o = 32; o; o >>= 1) m[h] = fmaxf(m[h], __shfl_xor(m[h], o));

    float denom[H], acc[H];
#pragma unroll
    for (int h = 0; h < H; ++h) { denom[h] = 0.f; acc[h] = 0.f; }
    for (int i = begin; i < end; ++i) {
        int s = csr_src[i];
        const float* fr = feat + (size_t)s * fstride + lane;
        if constexpr (H == 4) {
            float4 e4 = *(reinterpret_cast<const float4*>(el) + s);
            float w0 = __expf(leaky(e4.x + ern[0]) - m[0]);
            float w1 = __expf(leaky(e4.y + ern[1]) - m[1]);
            float w2 = __expf(leaky(e4.z + ern[2]) - m[2]);
            float w3 = __expf(leaky(e4.w + ern[3]) - m[3]);
            denom[0] += w0; denom[1] += w1; denom[2] += w2; denom[3] += w3;
            acc[0] = fmaf(w0, fr[0], acc[0]);
            acc[1] = fmaf(w1, fr[64], acc[1]);
            acc[2] = fmaf(w2, fr[128], acc[2]);
            acc[3] = fmaf(w3, fr[192], acc[3]);
        } else {
            float w = __expf(leaky(el[s] + ern[0]) - m[0]);
            denom[0] += w;
            acc[0] = fmaf(w, fr[0], acc[0]);
        }
    }

#pragma unroll
    for (int h = 0; h < H; ++h) {
        float o = (end > begin) ? acc[h] / denom[h] : 0.f;
        if constexpr (RES == 1) o += resbuf[(size_t)node * rstride + h * 64 + lane];
        if constexpr (RES == 2) o += resbuf[(size_t)node * rstride + lane];
        o += bias[h * 64 + lane];
        if constexpr (ACT) o = (o > 0.f) ? o : (__expf(o) - 1.f);
        out[(size_t)node * ostride + h * 64 + lane] = o;
    }
}

// ---------------- launch ----------------
extern "C" void kernel_launch(void* const* d_in, const int* in_sizes, int n_in, void* d_out,
                              int out_size, void* d_ws, size_t ws_size, hipStream_t stream) {
    const float* x   = (const float*)d_in[0];
    const int* src   = (const int*)d_in[1];
    const int* dst   = (const int*)d_in[2];
    const float* W0  = (const float*)d_in[3];
    const float* al0 = (const float*)d_in[4];
    const float* ar0 = (const float*)d_in[5];
    const float* b0  = (const float*)d_in[6];
    const float* W1  = (const float*)d_in[7];
    const float* al1 = (const float*)d_in[8];
    const float* ar1 = (const float*)d_in[9];
    const float* b1  = (const float*)d_in[10];
    const float* W2  = (const float*)d_in[11];
    const float* al2 = (const float*)d_in[12];
    const float* ar2 = (const float*)d_in[13];
    const float* b2  = (const float*)d_in[14];
    const float* Wr2 = (const float*)d_in[15];
    float* out = (float*)d_out;

    char* w = (char*)d_ws;
    size_t off = 0;
    auto alloc = [&](size_t bytes) -> char* {
        char* p = w + off;
        off += (bytes + 255) & ~(size_t)255;
        return p;
    };
    float* feat     = (float*)alloc((size_t)NNODES * 256 * 4);
    float* hbuf     = (float*)alloc((size_t)NNODES * 256 * 4);
    float* el       = (float*)alloc((size_t)NNODES * 4 * 4);
    float* er       = (float*)alloc((size_t)NNODES * 4 * 4);
    ushort* Bt0     = (ushort*)alloc(65536 * 2);
    ushort* Bt1     = (ushort*)alloc(65536 * 2);
    ushort* Bt2     = (ushort*)alloc(32768 * 2);
    int* counts     = (int*)alloc((size_t)NNODES * 4);
    int* cursor     = (int*)alloc((size_t)NNODES * 4);
    int* row_start  = (int*)alloc((size_t)(NNODES + 1) * 4);
    int* csr_src    = (int*)alloc((size_t)NEDGES * 4);

    hipMemsetAsync(counts, 0, (size_t)NNODES * 4, stream);
    hipMemsetAsync(cursor, 0, (size_t)NNODES * 4, stream);

    const int EB = (NEDGES + 255) / 256;
    const int NB4 = (NNODES + 3) / 4;
    const int NBM = (NNODES + 127) / 128;  // 391

    hist_kernel<<<EB, 256, 0, stream>>>(dst, counts);
    scan_kernel<<<1, 1024, 0, stream>>>(counts, row_start, NNODES);
    scatter_kernel<<<EB, 256, 0, stream>>>(src, dst, row_start, cursor, csr_src);
    pack_kernel<<<640, 256, 0, stream>>>(W0, W1, W2, Wr2, Bt0, Bt1, Bt2);

    // ---- layer 0
    gemm_mfma<256><<<dim3(NBM, 2), 256, 0, stream>>>(x, Bt0, feat, NNODES);
    elr_kernel<4><<<NB4, 256, 0, stream>>>(feat, 256, al0, ar0, el, er, NNODES);
    agg_kernel<4, 0, true><<<NB4, 256, 0, stream>>>(feat, 256, el, er, row_start, csr_src,
                                                    nullptr, 0, b0, hbuf, 256, NNODES);
    // ---- layer 1 (identity residual from hbuf, in-place out)
    gemm_mfma<256><<<dim3(NBM, 2), 256, 0, stream>>>(hbuf, Bt1, feat, NNODES);
    elr_kernel<4><<<NB4, 256, 0, stream>>>(feat, 256, al1, ar1, el, er, NNODES);
    agg_kernel<4, 1, true><<<NB4, 256, 0, stream>>>(feat, 256, el, er, row_start, csr_src,
                                                    hbuf, 256, b1, hbuf, 256, NNODES);
    // ---- layer 2: hbuf @ [W2|res_w2]^T -> feat[N,128]; cols 0..63 head, 64..127 lin residual
    gemm_mfma<128><<<dim3(NBM, 1), 256, 0, stream>>>(hbuf, Bt2, feat, NNODES);
    elr_kernel<1><<<NB4, 256, 0, stream>>>(feat, 128, al2, ar2, el, er, NNODES);
    agg_kernel<1, 2, false><<<NB4, 256, 0, stream>>>(feat, 128, el, er, row_start, csr_src,
                                                     feat + 64, 128, b2, out, 64, NNODES);
}

// Round 3
// 611.807 us; speedup vs baseline: 1.6363x; 1.2479x over previous
//
#include <hip/hip_runtime.h>
#include <math.h>

#define NNODES 50000
#define NEDGES 800000

__device__ __forceinline__ float leaky(float x) { return x > 0.f ? x : 0.2f * x; }

__device__ __forceinline__ ushort f2bf(float f) {
    unsigned u = __float_as_uint(f);
    return (ushort)((u + 0x7fffu + ((u >> 16) & 1u)) >> 16);  // RNE
}
__device__ __forceinline__ float bf2f(ushort u) {
    return __uint_as_float((unsigned)u << 16);
}

// ---------------- CSR build ----------------
__global__ void hist_kernel(const int* __restrict__ dst, int* __restrict__ counts) {
    int e = blockIdx.x * 256 + threadIdx.x;
    if (e < NEDGES) atomicAdd(&counts[dst[e]], 1);
}

// work-efficient single-block scan: each thread owns PER consecutive nodes
__global__ __launch_bounds__(1024) void scan_kernel(const int* __restrict__ counts,
                                                    int* __restrict__ row_start, int Nn) {
    __shared__ int sums[1024];
    const int tid = threadIdx.x;
    const int PER = (Nn + 1023) / 1024;
    const int base = tid * PER;
    int local = 0;
    for (int i = 0; i < PER; ++i) {
        int idx = base + i;
        if (idx < Nn) local += counts[idx];
    }
    sums[tid] = local;
    __syncthreads();
    for (int off = 1; off < 1024; off <<= 1) {
        int t = (tid >= off) ? sums[tid - off] : 0;
        __syncthreads();
        sums[tid] += t;
        __syncthreads();
    }
    int run = sums[tid] - local;  // exclusive prefix across threads
    for (int i = 0; i < PER; ++i) {
        int idx = base + i;
        if (idx < Nn) {
            row_start[idx] = run;
            run += counts[idx];
        }
    }
    if (tid == 1023) row_start[Nn] = run;
}

__global__ void scatter_kernel(const int* __restrict__ src, const int* __restrict__ dst,
                               const int* __restrict__ row_start, int* __restrict__ cursor,
                               int* __restrict__ csr_src) {
    int e = blockIdx.x * 256 + threadIdx.x;
    if (e < NEDGES) {
        int d = dst[e];
        int pos = row_start[d] + atomicAdd(&cursor[d], 1);
        csr_src[pos] = src[e];
    }
}

// ---------------- pack weights: Bt[n][k] bf16 (transposed + converted) ----------------
__global__ void pack_kernel(const float* __restrict__ W0, const float* __restrict__ W1,
                            const float* __restrict__ W2, const float* __restrict__ Wr,
                            ushort* __restrict__ Bt0, ushort* __restrict__ Bt1,
                            ushort* __restrict__ Bt2) {
    int idx = blockIdx.x * 256 + threadIdx.x;  // 0..163839
    if (idx < 65536) {
        int n = idx >> 8, k = idx & 255;
        Bt0[idx] = f2bf(W0[k * 256 + n]);
    } else if (idx < 131072) {
        int j = idx - 65536;
        int n = j >> 8, k = j & 255;
        Bt1[j] = f2bf(W1[k * 256 + n]);
    } else {
        int j = idx - 131072;
        int n = j >> 8, k = j & 255;
        Bt2[j] = f2bf(n < 64 ? W2[k * 64 + n] : Wr[k * 64 + (n - 64)]);
    }
}

// ---------------- MFMA GEMM: C[N,MCOLS] = A[N,256](f32) @ Bt[MCOLS,256]^T(bf16) ----------------
template <int MCOLS>
__global__ __launch_bounds__(256) void gemm_mfma(const float* __restrict__ A,
                                                 const ushort* __restrict__ Bt,
                                                 float* __restrict__ C, int Nrows) {
    using bf16x8 = __attribute__((ext_vector_type(8))) short;
    using f32x4 = __attribute__((ext_vector_type(4))) float;
    __shared__ ushort As[8192];  // 128 rows x 64 k, bf16
    __shared__ ushort Bs[8192];
    const int tid = threadIdx.x;
    const int lane = tid & 63;
    const int wave = tid >> 6;
    const int wr = wave >> 1, wc = wave & 1;
    const int q = lane >> 4, li = lane & 15;
    const int r0 = blockIdx.x * 128;
    const int n0 = blockIdx.y * 128;

    f32x4 acc[4][4];
#pragma unroll
    for (int i = 0; i < 4; ++i)
#pragma unroll
        for (int j = 0; j < 4; ++j) acc[i][j] = (f32x4){0.f, 0.f, 0.f, 0.f};

    for (int kk = 0; kk < 256; kk += 64) {
        __syncthreads();
#pragma unroll
        for (int j = 0; j < 4; ++j) {
            int g = j * 256 + tid;
            int m = g >> 3, kg = g & 7;
            int mf = m >> 4, mr = m & 15;
            int row = r0 + m;
            float4 v0 = make_float4(0.f, 0.f, 0.f, 0.f), v1 = v0;
            if (row < Nrows) {
                const float* p = A + (size_t)row * 256 + kk + kg * 8;
                v0 = *reinterpret_cast<const float4*>(p);
                v1 = *reinterpret_cast<const float4*>(p + 4);
            }
            union { bf16x8 v; ushort u[8]; } pk;
            pk.u[0] = f2bf(v0.x); pk.u[1] = f2bf(v0.y);
            pk.u[2] = f2bf(v0.z); pk.u[3] = f2bf(v0.w);
            pk.u[4] = f2bf(v1.x); pk.u[5] = f2bf(v1.y);
            pk.u[6] = f2bf(v1.z); pk.u[7] = f2bf(v1.w);
            *reinterpret_cast<bf16x8*>(&As[((mf * 8 + kg) * 16 + (mr ^ kg)) * 8]) = pk.v;
        }
#pragma unroll
        for (int j = 0; j < 4; ++j) {
            int g = j * 256 + tid;
            int n = g >> 3, kg = g & 7;
            int nf = n >> 4, nr = n & 15;
            bf16x8 v = *reinterpret_cast<const bf16x8*>(Bt + (size_t)(n0 + n) * 256 + kk + kg * 8);
            *reinterpret_cast<bf16x8*>(&Bs[((nf * 8 + kg) * 16 + (nr ^ kg)) * 8]) = v;
        }
        __syncthreads();
#pragma unroll
        for (int t = 0; t < 2; ++t) {
            const int kc = t * 4 + q;
            bf16x8 af[4], bfv[4];
#pragma unroll
            for (int f = 0; f < 4; ++f) {
                af[f] = *reinterpret_cast<const bf16x8*>(
                    &As[(((wr * 4 + f) * 8 + kc) * 16 + (li ^ kc)) * 8]);
                bfv[f] = *reinterpret_cast<const bf16x8*>(
                    &Bs[(((wc * 4 + f) * 8 + kc) * 16 + (li ^ kc)) * 8]);
            }
#pragma unroll
            for (int f = 0; f < 4; ++f)
#pragma unroll
                for (int f2 = 0; f2 < 4; ++f2)
                    acc[f][f2] =
                        __builtin_amdgcn_mfma_f32_16x16x32_bf16(af[f], bfv[f2], acc[f][f2], 0, 0, 0);
        }
    }
#pragma unroll
    for (int f = 0; f < 4; ++f) {
#pragma unroll
        for (int r = 0; r < 4; ++r) {
            int row = r0 + wr * 64 + f * 16 + q * 4 + r;
            if (row < Nrows) {
#pragma unroll
                for (int f2 = 0; f2 < 4; ++f2)
                    C[(size_t)row * MCOLS + n0 + wc * 64 + f2 * 16 + li] = acc[f][f2][r];
            }
        }
    }
}

// ---------------- el/er dot products + bf16 repack (interleaved for H=4) ----------------
// H=4: featb[n*256 + d*4 + h]; H=1: featb[n*64 + d]
template <int H>
__global__ __launch_bounds__(256) void elr_kernel(const float* __restrict__ feat, int fstride,
                                                  const float* __restrict__ al,
                                                  const float* __restrict__ ar,
                                                  float* __restrict__ el, float* __restrict__ er,
                                                  ushort* __restrict__ featb, int fbstride,
                                                  int Nn) {
    int node = blockIdx.x * 4 + (threadIdx.x >> 6);
    int lane = threadIdx.x & 63;
    if (node >= Nn) return;
#pragma unroll
    for (int h = 0; h < H; ++h) {
        float f = feat[(size_t)node * fstride + h * 64 + lane];
        if constexpr (H == 4)
            featb[(size_t)node * fbstride + lane * 4 + h] = f2bf(f);
        else
            featb[(size_t)node * fbstride + lane] = f2bf(f);
        float sl = f * al[h * 64 + lane];
        float sr = f * ar[h * 64 + lane];
        for (int o = 32; o; o >>= 1) {
            sl += __shfl_xor(sl, o);
            sr += __shfl_xor(sr, o);
        }
        if (lane == 0) {
            el[node * H + h] = sl;
            er[node * H + h] = sr;
        }
    }
}

// ---------------- per-dst-node softmax aggregation (one wave per node) ----------------
// Weights computed lane-parallel (once per edge), broadcast via per-wave LDS scratch.
// Messages gathered as bf16 (interleaved [d][h] for H=4).
template <int H, int RES, bool ACT>
__global__ __launch_bounds__(256) void agg_kernel(
    const ushort* __restrict__ featb, int fstride, const float* __restrict__ el,
    const float* __restrict__ er, const int* __restrict__ row_start,
    const int* __restrict__ csr_src, const float* __restrict__ resbuf, int rstride,
    const float* __restrict__ bias, float* __restrict__ out, int ostride, int Nn) {
    __shared__ float wbuf[4][64 * H];
    __shared__ int obuf[4][64];
    const int wv = threadIdx.x >> 6, lane = threadIdx.x & 63;
    int node = blockIdx.x * 4 + wv;
    if (node >= Nn) return;

    int begin = row_start[node], end = row_start[node + 1];

    float ern[H];
    if constexpr (H == 4) {
        float4 e4 = *(reinterpret_cast<const float4*>(er) + node);
        ern[0] = e4.x; ern[1] = e4.y; ern[2] = e4.z; ern[3] = e4.w;
    } else {
        ern[0] = er[node];
    }

    // pass 1: global per-head max (lanes parallelize edges)
    float m[H];
#pragma unroll
    for (int h = 0; h < H; ++h) m[h] = -INFINITY;
    for (int i = begin + lane; i < end; i += 64) {
        int s = csr_src[i];
        if constexpr (H == 4) {
            float4 e4 = *(reinterpret_cast<const float4*>(el) + s);
            m[0] = fmaxf(m[0], leaky(e4.x + ern[0]));
            m[1] = fmaxf(m[1], leaky(e4.y + ern[1]));
            m[2] = fmaxf(m[2], leaky(e4.z + ern[2]));
            m[3] = fmaxf(m[3], leaky(e4.w + ern[3]));
        } else {
            m[0] = fmaxf(m[0], leaky(el[s] + ern[0]));
        }
    }
#pragma unroll
    for (int h = 0; h < H; ++h)
        for (int o = 32; o; o >>= 1) m[h] = fmaxf(m[h], __shfl_xor(m[h], o));

    // pass 2: chunked — weights lane-parallel into LDS, then broadcast accumulate
    float denom[H], acc[H];
#pragma unroll
    for (int h = 0; h < H; ++h) { denom[h] = 0.f; acc[h] = 0.f; }

    for (int c = begin; c < end; c += 64) {
        int nE = min(64, end - c);
        int s = (lane < nE) ? csr_src[c + lane] : 0;
        float w[H];
        if constexpr (H == 4) {
            float4 e4 = *(reinterpret_cast<const float4*>(el) + s);
            w[0] = __expf(leaky(e4.x + ern[0]) - m[0]);
            w[1] = __expf(leaky(e4.y + ern[1]) - m[1]);
            w[2] = __expf(leaky(e4.z + ern[2]) - m[2]);
            w[3] = __expf(leaky(e4.w + ern[3]) - m[3]);
        } else {
            w[0] = __expf(leaky(el[s] + ern[0]) - m[0]);
        }
        if (lane >= nE) {
#pragma unroll
            for (int h = 0; h < H; ++h) w[h] = 0.f;
        }
#pragma unroll
        for (int h = 0; h < H; ++h) denom[h] += w[h];
        obuf[wv][lane] = s * fstride;
        if constexpr (H == 4)
            *reinterpret_cast<float4*>(&wbuf[wv][lane * 4]) = make_float4(w[0], w[1], w[2], w[3]);
        else
            wbuf[wv][lane] = w[0];
        __asm__ volatile("s_waitcnt lgkmcnt(0)" ::: "memory");

#pragma unroll 2
        for (int e = 0; e < nE; ++e) {
            int off = obuf[wv][e];
            if constexpr (H == 4) {
                float4 we = *reinterpret_cast<const float4*>(&wbuf[wv][e * 4]);
                ushort4 f4 = *reinterpret_cast<const ushort4*>(featb + off + lane * 4);
                acc[0] = fmaf(we.x, bf2f(f4.x), acc[0]);
                acc[1] = fmaf(we.y, bf2f(f4.y), acc[1]);
                acc[2] = fmaf(we.z, bf2f(f4.z), acc[2]);
                acc[3] = fmaf(we.w, bf2f(f4.w), acc[3]);
            } else {
                float we = wbuf[wv][e];
                acc[0] = fmaf(we, bf2f(featb[off + lane]), acc[0]);
            }
        }
        __asm__ volatile("" ::: "memory");
    }

    // reduce denom across lanes
#pragma unroll
    for (int h = 0; h < H; ++h)
        for (int o = 32; o; o >>= 1) denom[h] += __shfl_xor(denom[h], o);

#pragma unroll
    for (int h = 0; h < H; ++h) {
        float o = (end > begin) ? acc[h] / denom[h] : 0.f;
        if constexpr (RES == 1) o += resbuf[(size_t)node * rstride + h * 64 + lane];
        if constexpr (RES == 2) o += resbuf[(size_t)node * rstride + lane];
        o += bias[h * 64 + lane];
        if constexpr (ACT) o = (o > 0.f) ? o : (__expf(o) - 1.f);
        out[(size_t)node * ostride + h * 64 + lane] = o;
    }
}

// ---------------- launch ----------------
extern "C" void kernel_launch(void* const* d_in, const int* in_sizes, int n_in, void* d_out,
                              int out_size, void* d_ws, size_t ws_size, hipStream_t stream) {
    const float* x   = (const float*)d_in[0];
    const int* src   = (const int*)d_in[1];
    const int* dst   = (const int*)d_in[2];
    const float* W0  = (const float*)d_in[3];
    const float* al0 = (const float*)d_in[4];
    const float* ar0 = (const float*)d_in[5];
    const float* b0  = (const float*)d_in[6];
    const float* W1  = (const float*)d_in[7];
    const float* al1 = (const float*)d_in[8];
    const float* ar1 = (const float*)d_in[9];
    const float* b1  = (const float*)d_in[10];
    const float* W2  = (const float*)d_in[11];
    const float* al2 = (const float*)d_in[12];
    const float* ar2 = (const float*)d_in[13];
    const float* b2  = (const float*)d_in[14];
    const float* Wr2 = (const float*)d_in[15];
    float* out = (float*)d_out;

    char* w = (char*)d_ws;
    size_t off = 0;
    auto alloc = [&](size_t bytes) -> char* {
        char* p = w + off;
        off += (bytes + 255) & ~(size_t)255;
        return p;
    };
    float* feat     = (float*)alloc((size_t)NNODES * 256 * 4);
    float* hbuf     = (float*)alloc((size_t)NNODES * 256 * 4);
    ushort* featb   = (ushort*)alloc((size_t)NNODES * 256 * 2);  // bf16 messages (reused per layer)
    float* el       = (float*)alloc((size_t)NNODES * 4 * 4);
    float* er       = (float*)alloc((size_t)NNODES * 4 * 4);
    ushort* Bt0     = (ushort*)alloc(65536 * 2);
    ushort* Bt1     = (ushort*)alloc(65536 * 2);
    ushort* Bt2     = (ushort*)alloc(32768 * 2);
    int* counts     = (int*)alloc((size_t)NNODES * 4);
    int* cursor     = (int*)alloc((size_t)NNODES * 4);
    int* row_start  = (int*)alloc((size_t)(NNODES + 1) * 4);
    int* csr_src    = (int*)alloc((size_t)NEDGES * 4);

    hipMemsetAsync(counts, 0, (size_t)NNODES * 4, stream);
    hipMemsetAsync(cursor, 0, (size_t)NNODES * 4, stream);

    const int EB = (NEDGES + 255) / 256;
    const int NB4 = (NNODES + 3) / 4;
    const int NBM = (NNODES + 127) / 128;

    hist_kernel<<<EB, 256, 0, stream>>>(dst, counts);
    scan_kernel<<<1, 1024, 0, stream>>>(counts, row_start, NNODES);
    scatter_kernel<<<EB, 256, 0, stream>>>(src, dst, row_start, cursor, csr_src);
    pack_kernel<<<640, 256, 0, stream>>>(W0, W1, W2, Wr2, Bt0, Bt1, Bt2);

    // ---- layer 0
    gemm_mfma<256><<<dim3(NBM, 2), 256, 0, stream>>>(x, Bt0, feat, NNODES);
    elr_kernel<4><<<NB4, 256, 0, stream>>>(feat, 256, al0, ar0, el, er, featb, 256, NNODES);
    agg_kernel<4, 0, true><<<NB4, 256, 0, stream>>>(featb, 256, el, er, row_start, csr_src,
                                                    nullptr, 0, b0, hbuf, 256, NNODES);
    // ---- layer 1 (identity residual from hbuf, in-place out)
    gemm_mfma<256><<<dim3(NBM, 2), 256, 0, stream>>>(hbuf, Bt1, feat, NNODES);
    elr_kernel<4><<<NB4, 256, 0, stream>>>(feat, 256, al1, ar1, el, er, featb, 256, NNODES);
    agg_kernel<4, 1, true><<<NB4, 256, 0, stream>>>(featb, 256, el, er, row_start, csr_src,
                                                    hbuf, 256, b1, hbuf, 256, NNODES);
    // ---- layer 2: hbuf @ [W2|res_w2]^T -> feat[N,128]; cols 0..63 head, 64..127 lin residual
    gemm_mfma<128><<<dim3(NBM, 1), 256, 0, stream>>>(hbuf, Bt2, feat, NNODES);
    elr_kernel<1><<<NB4, 256, 0, stream>>>(feat, 128, al2, ar2, el, er, featb, 64, NNODES);
    agg_kernel<1, 2, false><<<NB4, 256, 0, stream>>>(featb, 64, el, er, row_start, csr_src,
                                                     feat + 64, 128, b2, out, 64, NNODES);
}

// Round 4
// 518.457 us; speedup vs baseline: 1.9309x; 1.1801x over previous
//
#include <hip/hip_runtime.h>
#include <math.h>

#define NNODES 50000
#define NEDGES 800000

__device__ __forceinline__ float leaky(float x) { return x > 0.f ? x : 0.2f * x; }

__device__ __forceinline__ ushort f2bf(float f) {
    unsigned u = __float_as_uint(f);
    return (ushort)((u + 0x7fffu + ((u >> 16) & 1u)) >> 16);  // RNE
}
__device__ __forceinline__ float bf2f(ushort u) {
    return __uint_as_float((unsigned)u << 16);
}

// ---------------- CSR build ----------------
__global__ void hist_kernel(const int* __restrict__ dst, int* __restrict__ counts) {
    int e = blockIdx.x * 256 + threadIdx.x;
    if (e < NEDGES) atomicAdd(&counts[dst[e]], 1);
}

// phase 1: per-block (1024 nodes) sums
__global__ __launch_bounds__(256) void scan_partial(const int* __restrict__ counts,
                                                    int* __restrict__ bsum, int Nn) {
    int b = blockIdx.x, t = threadIdx.x;
    int base = b * 1024;
    int v = 0;
#pragma unroll
    for (int i = 0; i < 4; ++i) {
        int idx = base + t + 256 * i;
        if (idx < Nn) v += counts[idx];
    }
    for (int o = 32; o; o >>= 1) v += __shfl_xor(v, o);
    __shared__ int ws[4];
    if ((t & 63) == 0) ws[t >> 6] = v;
    __syncthreads();
    if (t == 0) bsum[b] = ws[0] + ws[1] + ws[2] + ws[3];
}

// phase 2: each block scans its 1024 counts; block offset = serial prefix of bsum
__global__ __launch_bounds__(256) void scan_final(const int* __restrict__ counts,
                                                  const int* __restrict__ bsum,
                                                  int* __restrict__ row_start, int Nn, int nB) {
    __shared__ int off_s;
    __shared__ int tsum[256];
    int b = blockIdx.x, t = threadIdx.x;
    if (t == 0) {
        int o = 0;
        for (int i = 0; i < b; ++i) o += bsum[i];
        off_s = o;
    }
    int base = b * 1024 + t * 4;
    int c0 = 0, c1 = 0, c2 = 0, c3 = 0;
    if (base + 3 < Nn) {
        int4 c = *reinterpret_cast<const int4*>(counts + base);
        c0 = c.x; c1 = c.y; c2 = c.z; c3 = c.w;
    } else {
        if (base + 0 < Nn) c0 = counts[base + 0];
        if (base + 1 < Nn) c1 = counts[base + 1];
        if (base + 2 < Nn) c2 = counts[base + 2];
        if (base + 3 < Nn) c3 = counts[base + 3];
    }
    int s0 = c0, s1 = s0 + c1, s2 = s1 + c2, s3 = s2 + c3;  // inclusive in-thread
    tsum[t] = s3;
    __syncthreads();
    for (int o = 1; o < 256; o <<= 1) {
        int u = (t >= o) ? tsum[t - o] : 0;
        __syncthreads();
        tsum[t] += u;
        __syncthreads();
    }
    int o = off_s + tsum[t] - s3;  // exclusive prefix for node `base`
    if (base + 3 < Nn) {
        *reinterpret_cast<int4*>(row_start + base) = make_int4(o, o + s0, o + s1, o + s2);
    } else {
        if (base + 0 < Nn) row_start[base + 0] = o;
        if (base + 1 < Nn) row_start[base + 1] = o + s0;
        if (base + 2 < Nn) row_start[base + 2] = o + s1;
        if (base + 3 < Nn) row_start[base + 3] = o + s2;
    }
    if (b == nB - 1 && t == 255) row_start[Nn] = off_s + tsum[255];
}

__global__ void scatter_kernel(const int* __restrict__ src, const int* __restrict__ dst,
                               const int* __restrict__ row_start, int* __restrict__ cursor,
                               int* __restrict__ csr_src) {
    int e = blockIdx.x * 256 + threadIdx.x;
    if (e < NEDGES) {
        int d = dst[e];
        int pos = row_start[d] + atomicAdd(&cursor[d], 1);
        csr_src[pos] = src[e];
    }
}

// ---------------- pack weights: Bt[n][k] bf16 (transposed + converted) ----------------
__global__ void pack_kernel(const float* __restrict__ W0, const float* __restrict__ W1,
                            const float* __restrict__ W2, const float* __restrict__ Wr,
                            ushort* __restrict__ Bt0, ushort* __restrict__ Bt1,
                            ushort* __restrict__ Bt2) {
    int idx = blockIdx.x * 256 + threadIdx.x;  // 0..163839
    if (idx < 65536) {
        int n = idx >> 8, k = idx & 255;
        Bt0[idx] = f2bf(W0[k * 256 + n]);
    } else if (idx < 131072) {
        int j = idx - 65536;
        int n = j >> 8, k = j & 255;
        Bt1[j] = f2bf(W1[k * 256 + n]);
    } else {
        int j = idx - 131072;
        int n = j >> 8, k = j & 255;
        Bt2[j] = f2bf(n < 64 ? W2[k * 64 + n] : Wr[k * 64 + (n - 64)]);
    }
}

// ---------------- MFMA GEMM: C[N,MCOLS] = A[N,256](f32) @ Bt[MCOLS,256]^T(bf16) ----------------
template <int MCOLS>
__global__ __launch_bounds__(256) void gemm_mfma(const float* __restrict__ A,
                                                 const ushort* __restrict__ Bt,
                                                 float* __restrict__ C, int Nrows) {
    using bf16x8 = __attribute__((ext_vector_type(8))) short;
    using f32x4 = __attribute__((ext_vector_type(4))) float;
    __shared__ ushort As[8192];  // 128 rows x 64 k, bf16
    __shared__ ushort Bs[8192];
    const int tid = threadIdx.x;
    const int lane = tid & 63;
    const int wave = tid >> 6;
    const int wr = wave >> 1, wc = wave & 1;
    const int q = lane >> 4, li = lane & 15;
    const int r0 = blockIdx.x * 128;
    const int n0 = blockIdx.y * 128;

    f32x4 acc[4][4];
#pragma unroll
    for (int i = 0; i < 4; ++i)
#pragma unroll
        for (int j = 0; j < 4; ++j) acc[i][j] = (f32x4){0.f, 0.f, 0.f, 0.f};

    for (int kk = 0; kk < 256; kk += 64) {
        __syncthreads();
#pragma unroll
        for (int j = 0; j < 4; ++j) {
            int g = j * 256 + tid;
            int m = g >> 3, kg = g & 7;
            int mf = m >> 4, mr = m & 15;
            int row = r0 + m;
            float4 v0 = make_float4(0.f, 0.f, 0.f, 0.f), v1 = v0;
            if (row < Nrows) {
                const float* p = A + (size_t)row * 256 + kk + kg * 8;
                v0 = *reinterpret_cast<const float4*>(p);
                v1 = *reinterpret_cast<const float4*>(p + 4);
            }
            union { bf16x8 v; ushort u[8]; } pk;
            pk.u[0] = f2bf(v0.x); pk.u[1] = f2bf(v0.y);
            pk.u[2] = f2bf(v0.z); pk.u[3] = f2bf(v0.w);
            pk.u[4] = f2bf(v1.x); pk.u[5] = f2bf(v1.y);
            pk.u[6] = f2bf(v1.z); pk.u[7] = f2bf(v1.w);
            *reinterpret_cast<bf16x8*>(&As[((mf * 8 + kg) * 16 + (mr ^ kg)) * 8]) = pk.v;
        }
#pragma unroll
        for (int j = 0; j < 4; ++j) {
            int g = j * 256 + tid;
            int n = g >> 3, kg = g & 7;
            int nf = n >> 4, nr = n & 15;
            bf16x8 v = *reinterpret_cast<const bf16x8*>(Bt + (size_t)(n0 + n) * 256 + kk + kg * 8);
            *reinterpret_cast<bf16x8*>(&Bs[((nf * 8 + kg) * 16 + (nr ^ kg)) * 8]) = v;
        }
        __syncthreads();
#pragma unroll
        for (int t = 0; t < 2; ++t) {
            const int kc = t * 4 + q;
            bf16x8 af[4], bfv[4];
#pragma unroll
            for (int f = 0; f < 4; ++f) {
                af[f] = *reinterpret_cast<const bf16x8*>(
                    &As[(((wr * 4 + f) * 8 + kc) * 16 + (li ^ kc)) * 8]);
                bfv[f] = *reinterpret_cast<const bf16x8*>(
                    &Bs[(((wc * 4 + f) * 8 + kc) * 16 + (li ^ kc)) * 8]);
            }
#pragma unroll
            for (int f = 0; f < 4; ++f)
#pragma unroll
                for (int f2 = 0; f2 < 4; ++f2)
                    acc[f][f2] =
                        __builtin_amdgcn_mfma_f32_16x16x32_bf16(af[f], bfv[f2], acc[f][f2], 0, 0, 0);
        }
    }
#pragma unroll
    for (int f = 0; f < 4; ++f) {
#pragma unroll
        for (int r = 0; r < 4; ++r) {
            int row = r0 + wr * 64 + f * 16 + q * 4 + r;
            if (row < Nrows) {
#pragma unroll
                for (int f2 = 0; f2 < 4; ++f2)
                    C[(size_t)row * MCOLS + n0 + wc * 64 + f2 * 16 + li] = acc[f][f2][r];
            }
        }
    }
}

// ---------------- el/er dot products + bf16 repack (interleaved for H=4) ----------------
template <int H>
__global__ __launch_bounds__(256) void elr_kernel(const float* __restrict__ feat, int fstride,
                                                  const float* __restrict__ al,
                                                  const float* __restrict__ ar,
                                                  float* __restrict__ el, float* __restrict__ er,
                                                  ushort* __restrict__ featb, int fbstride,
                                                  int Nn) {
    int node = blockIdx.x * 4 + (threadIdx.x >> 6);
    int lane = threadIdx.x & 63;
    if (node >= Nn) return;
#pragma unroll
    for (int h = 0; h < H; ++h) {
        float f = feat[(size_t)node * fstride + h * 64 + lane];
        if constexpr (H == 4)
            featb[(size_t)node * fbstride + lane * 4 + h] = f2bf(f);
        else
            featb[(size_t)node * fbstride + lane] = f2bf(f);
        float sl = f * al[h * 64 + lane];
        float sr = f * ar[h * 64 + lane];
        for (int o = 32; o; o >>= 1) {
            sl += __shfl_xor(sl, o);
            sr += __shfl_xor(sr, o);
        }
        if (lane == 0) {
            el[node * H + h] = sl;
            er[node * H + h] = sr;
        }
    }
}

// ---------------- per-dst-node softmax aggregation (one wave per node) ----------------
template <int H, int RES, bool ACT>
__global__ __launch_bounds__(256) void agg_kernel(
    const ushort* __restrict__ featb, int fstride, const float* __restrict__ el,
    const float* __restrict__ er, const int* __restrict__ row_start,
    const int* __restrict__ csr_src, const float* __restrict__ resbuf, int rstride,
    const float* __restrict__ bias, float* __restrict__ out, int ostride, int Nn) {
    __shared__ float wbuf[4][64 * H];
    __shared__ int obuf[4][64];
    const int wv = threadIdx.x >> 6, lane = threadIdx.x & 63;
    int node = blockIdx.x * 4 + wv;
    if (node >= Nn) return;

    int begin = row_start[node], end = row_start[node + 1];

    float ern[H];
    if constexpr (H == 4) {
        float4 e4 = *(reinterpret_cast<const float4*>(er) + node);
        ern[0] = e4.x; ern[1] = e4.y; ern[2] = e4.z; ern[3] = e4.w;
    } else {
        ern[0] = er[node];
    }

    float m[H];
#pragma unroll
    for (int h = 0; h < H; ++h) m[h] = -INFINITY;
    for (int i = begin + lane; i < end; i += 64) {
        int s = csr_src[i];
        if constexpr (H == 4) {
            float4 e4 = *(reinterpret_cast<const float4*>(el) + s);
            m[0] = fmaxf(m[0], leaky(e4.x + ern[0]));
            m[1] = fmaxf(m[1], leaky(e4.y + ern[1]));
            m[2] = fmaxf(m[2], leaky(e4.z + ern[2]));
            m[3] = fmaxf(m[3], leaky(e4.w + ern[3]));
        } else {
            m[0] = fmaxf(m[0], leaky(el[s] + ern[0]));
        }
    }
#pragma unroll
    for (int h = 0; h < H; ++h)
        for (int o = 32; o; o >>= 1) m[h] = fmaxf(m[h], __shfl_xor(m[h], o));

    float denom[H], acc[H];
#pragma unroll
    for (int h = 0; h < H; ++h) { denom[h] = 0.f; acc[h] = 0.f; }

    for (int c = begin; c < end; c += 64) {
        int nE = min(64, end - c);
        int s = (lane < nE) ? csr_src[c + lane] : 0;
        float w[H];
        if constexpr (H == 4) {
            float4 e4 = *(reinterpret_cast<const float4*>(el) + s);
            w[0] = __expf(leaky(e4.x + ern[0]) - m[0]);
            w[1] = __expf(leaky(e4.y + ern[1]) - m[1]);
            w[2] = __expf(leaky(e4.z + ern[2]) - m[2]);
            w[3] = __expf(leaky(e4.w + ern[3]) - m[3]);
        } else {
            w[0] = __expf(leaky(el[s] + ern[0]) - m[0]);
        }
        if (lane >= nE) {
#pragma unroll
            for (int h = 0; h < H; ++h) w[h] = 0.f;
        }
#pragma unroll
        for (int h = 0; h < H; ++h) denom[h] += w[h];
        obuf[wv][lane] = s * fstride;
        if constexpr (H == 4)
            *reinterpret_cast<float4*>(&wbuf[wv][lane * 4]) = make_float4(w[0], w[1], w[2], w[3]);
        else
            wbuf[wv][lane] = w[0];
        __asm__ volatile("s_waitcnt lgkmcnt(0)" ::: "memory");

#pragma unroll 2
        for (int e = 0; e < nE; ++e) {
            int off = obuf[wv][e];
            if constexpr (H == 4) {
                float4 we = *reinterpret_cast<const float4*>(&wbuf[wv][e * 4]);
                ushort4 f4 = *reinterpret_cast<const ushort4*>(featb + off + lane * 4);
                acc[0] = fmaf(we.x, bf2f(f4.x), acc[0]);
                acc[1] = fmaf(we.y, bf2f(f4.y), acc[1]);
                acc[2] = fmaf(we.z, bf2f(f4.z), acc[2]);
                acc[3] = fmaf(we.w, bf2f(f4.w), acc[3]);
            } else {
                float we = wbuf[wv][e];
                acc[0] = fmaf(we, bf2f(featb[off + lane]), acc[0]);
            }
        }
        __asm__ volatile("" ::: "memory");
    }

#pragma unroll
    for (int h = 0; h < H; ++h)
        for (int o = 32; o; o >>= 1) denom[h] += __shfl_xor(denom[h], o);

#pragma unroll
    for (int h = 0; h < H; ++h) {
        float o = (end > begin) ? acc[h] / denom[h] : 0.f;
        if constexpr (RES == 1) o += resbuf[(size_t)node * rstride + h * 64 + lane];
        if constexpr (RES == 2) o += resbuf[(size_t)node * rstride + lane];
        o += bias[h * 64 + lane];
        if constexpr (ACT) o = (o > 0.f) ? o : (__expf(o) - 1.f);
        out[(size_t)node * ostride + h * 64 + lane] = o;
    }
}

// ---------------- launch ----------------
extern "C" void kernel_launch(void* const* d_in, const int* in_sizes, int n_in, void* d_out,
                              int out_size, void* d_ws, size_t ws_size, hipStream_t stream) {
    const float* x   = (const float*)d_in[0];
    const int* src   = (const int*)d_in[1];
    const int* dst   = (const int*)d_in[2];
    const float* W0  = (const float*)d_in[3];
    const float* al0 = (const float*)d_in[4];
    const float* ar0 = (const float*)d_in[5];
    const float* b0  = (const float*)d_in[6];
    const float* W1  = (const float*)d_in[7];
    const float* al1 = (const float*)d_in[8];
    const float* ar1 = (const float*)d_in[9];
    const float* b1  = (const float*)d_in[10];
    const float* W2  = (const float*)d_in[11];
    const float* al2 = (const float*)d_in[12];
    const float* ar2 = (const float*)d_in[13];
    const float* b2  = (const float*)d_in[14];
    const float* Wr2 = (const float*)d_in[15];
    float* out = (float*)d_out;

    char* w = (char*)d_ws;
    size_t off = 0;
    auto alloc = [&](size_t bytes) -> char* {
        char* p = w + off;
        off += (bytes + 255) & ~(size_t)255;
        return p;
    };
    float* feat     = (float*)alloc((size_t)NNODES * 256 * 4);
    float* hbuf     = (float*)alloc((size_t)NNODES * 256 * 4);
    ushort* featb   = (ushort*)alloc((size_t)NNODES * 256 * 2);
    float* el       = (float*)alloc((size_t)NNODES * 4 * 4);
    float* er       = (float*)alloc((size_t)NNODES * 4 * 4);
    ushort* Bt0     = (ushort*)alloc(65536 * 2);
    ushort* Bt1     = (ushort*)alloc(65536 * 2);
    ushort* Bt2     = (ushort*)alloc(32768 * 2);
    // counts + cursor contiguous (single memset)
    int* counts     = (int*)alloc((size_t)NNODES * 4 * 2);
    int* cursor     = counts + NNODES;
    int* row_start  = (int*)alloc((size_t)(NNODES + 1) * 4);
    int* bsum       = (int*)alloc(64 * 4);
    int* csr_src    = (int*)alloc((size_t)NEDGES * 4);

    hipMemsetAsync(counts, 0, (size_t)NNODES * 4 * 2, stream);

    const int EB = (NEDGES + 255) / 256;
    const int NB4 = (NNODES + 3) / 4;
    const int NBM = (NNODES + 127) / 128;
    const int NSB = (NNODES + 1023) / 1024;  // 49

    hist_kernel<<<EB, 256, 0, stream>>>(dst, counts);
    scan_partial<<<NSB, 256, 0, stream>>>(counts, bsum, NNODES);
    scan_final<<<NSB, 256, 0, stream>>>(counts, bsum, row_start, NNODES, NSB);
    scatter_kernel<<<EB, 256, 0, stream>>>(src, dst, row_start, cursor, csr_src);
    pack_kernel<<<640, 256, 0, stream>>>(W0, W1, W2, Wr2, Bt0, Bt1, Bt2);

    // ---- layer 0
    gemm_mfma<256><<<dim3(NBM, 2), 256, 0, stream>>>(x, Bt0, feat, NNODES);
    elr_kernel<4><<<NB4, 256, 0, stream>>>(feat, 256, al0, ar0, el, er, featb, 256, NNODES);
    agg_kernel<4, 0, true><<<NB4, 256, 0, stream>>>(featb, 256, el, er, row_start, csr_src,
                                                    nullptr, 0, b0, hbuf, 256, NNODES);
    // ---- layer 1 (identity residual from hbuf, in-place out)
    gemm_mfma<256><<<dim3(NBM, 2), 256, 0, stream>>>(hbuf, Bt1, feat, NNODES);
    elr_kernel<4><<<NB4, 256, 0, stream>>>(feat, 256, al1, ar1, el, er, featb, 256, NNODES);
    agg_kernel<4, 1, true><<<NB4, 256, 0, stream>>>(featb, 256, el, er, row_start, csr_src,
                                                    hbuf, 256, b1, hbuf, 256, NNODES);
    // ---- layer 2
    gemm_mfma<128><<<dim3(NBM, 1), 256, 0, stream>>>(hbuf, Bt2, feat, NNODES);
    elr_kernel<1><<<NB4, 256, 0, stream>>>(feat, 128, al2, ar2, el, er, featb, 64, NNODES);
    agg_kernel<1, 2, false><<<NB4, 256, 0, stream>>>(featb, 64, el, er, row_start, csr_src,
                                                     feat + 64, 128, b2, out, 64, NNODES);
}

// Round 5
// 472.217 us; speedup vs baseline: 2.1200x; 1.0979x over previous
//
#include <hip/hip_runtime.h>
#include <math.h>

#define NNODES 50000
#define NEDGES 800000

__device__ __forceinline__ float leaky(float x) { return x > 0.f ? x : 0.2f * x; }

__device__ __forceinline__ ushort f2bf(float f) {
    unsigned u = __float_as_uint(f);
    return (ushort)((u + 0x7fffu + ((u >> 16) & 1u)) >> 16);  // RNE
}
__device__ __forceinline__ float bf2f(ushort u) {
    return __uint_as_float((unsigned)u << 16);
}

// ---------------- CSR build ----------------
__global__ void hist_kernel(const int* __restrict__ dst, int* __restrict__ counts) {
    int e = blockIdx.x * 256 + threadIdx.x;
    if (e < NEDGES) atomicAdd(&counts[dst[e]], 1);
}

__global__ __launch_bounds__(256) void scan_partial(const int* __restrict__ counts,
                                                    int* __restrict__ bsum, int Nn) {
    int b = blockIdx.x, t = threadIdx.x;
    int base = b * 1024;
    int v = 0;
#pragma unroll
    for (int i = 0; i < 4; ++i) {
        int idx = base + t + 256 * i;
        if (idx < Nn) v += counts[idx];
    }
    for (int o = 32; o; o >>= 1) v += __shfl_xor(v, o);
    __shared__ int ws[4];
    if ((t & 63) == 0) ws[t >> 6] = v;
    __syncthreads();
    if (t == 0) bsum[b] = ws[0] + ws[1] + ws[2] + ws[3];
}

__global__ __launch_bounds__(256) void scan_final(const int* __restrict__ counts,
                                                  const int* __restrict__ bsum,
                                                  int* __restrict__ row_start, int Nn, int nB) {
    __shared__ int off_s;
    __shared__ int tsum[256];
    int b = blockIdx.x, t = threadIdx.x;
    if (t == 0) {
        int o = 0;
        for (int i = 0; i < b; ++i) o += bsum[i];
        off_s = o;
    }
    int base = b * 1024 + t * 4;
    int c0 = 0, c1 = 0, c2 = 0, c3 = 0;
    if (base + 3 < Nn) {
        int4 c = *reinterpret_cast<const int4*>(counts + base);
        c0 = c.x; c1 = c.y; c2 = c.z; c3 = c.w;
    } else {
        if (base + 0 < Nn) c0 = counts[base + 0];
        if (base + 1 < Nn) c1 = counts[base + 1];
        if (base + 2 < Nn) c2 = counts[base + 2];
        if (base + 3 < Nn) c3 = counts[base + 3];
    }
    int s0 = c0, s1 = s0 + c1, s2 = s1 + c2, s3 = s2 + c3;
    tsum[t] = s3;
    __syncthreads();
    for (int o = 1; o < 256; o <<= 1) {
        int u = (t >= o) ? tsum[t - o] : 0;
        __syncthreads();
        tsum[t] += u;
        __syncthreads();
    }
    int o = off_s + tsum[t] - s3;
    if (base + 3 < Nn) {
        *reinterpret_cast<int4*>(row_start + base) = make_int4(o, o + s0, o + s1, o + s2);
    } else {
        if (base + 0 < Nn) row_start[base + 0] = o;
        if (base + 1 < Nn) row_start[base + 1] = o + s0;
        if (base + 2 < Nn) row_start[base + 2] = o + s1;
        if (base + 3 < Nn) row_start[base + 3] = o + s2;
    }
    if (b == nB - 1 && t == 255) row_start[Nn] = off_s + tsum[255];
}

__global__ void scatter_kernel(const int* __restrict__ src, const int* __restrict__ dst,
                               const int* __restrict__ row_start, int* __restrict__ cursor,
                               int* __restrict__ csr_src) {
    int e = blockIdx.x * 256 + threadIdx.x;
    if (e < NEDGES) {
        int d = dst[e];
        int pos = row_start[d] + atomicAdd(&cursor[d], 1);
        csr_src[pos] = src[e];
    }
}

// ---------------- pack weights: Bt[n][k] bf16 (transposed + converted) ----------------
__global__ void pack_kernel(const float* __restrict__ W0, const float* __restrict__ W1,
                            const float* __restrict__ W2, const float* __restrict__ Wr,
                            ushort* __restrict__ Bt0, ushort* __restrict__ Bt1,
                            ushort* __restrict__ Bt2) {
    int idx = blockIdx.x * 256 + threadIdx.x;  // 0..163839
    if (idx < 65536) {
        int n = idx >> 8, k = idx & 255;
        Bt0[idx] = f2bf(W0[k * 256 + n]);
    } else if (idx < 131072) {
        int j = idx - 65536;
        int n = j >> 8, k = j & 255;
        Bt1[j] = f2bf(W1[k * 256 + n]);
    } else {
        int j = idx - 131072;
        int n = j >> 8, k = j & 255;
        Bt2[j] = f2bf(n < 64 ? W2[k * 64 + n] : Wr[k * 64 + (n - 64)]);
    }
}

// ---- MFMA GEMM fused with el/er + bf16 repack epilogue ----
// C = A[N,256](f32) @ Bt[MCOLS,256]^T(bf16). No fp32 C write for MCOLS=256;
// instead: featb (bf16, head-interleaved) + el/er dot products.
// MCOLS=128 (layer 2): wc=0 half -> featb[n][d] + el/er; wc=1 half -> fp32 residual.
template <int MCOLS>
__global__ __launch_bounds__(256) void gemm_mfma(const float* __restrict__ A,
                                                 const ushort* __restrict__ Bt,
                                                 const float* __restrict__ al,
                                                 const float* __restrict__ ar,
                                                 ushort* __restrict__ featb,
                                                 float* __restrict__ el, float* __restrict__ er,
                                                 float* __restrict__ resid, int Nrows) {
    using bf16x8 = __attribute__((ext_vector_type(8))) short;
    using f32x4 = __attribute__((ext_vector_type(4))) float;
    __shared__ ushort As[8192];  // 128 rows x 64 k, bf16
    __shared__ ushort Bs[8192];
    const int tid = threadIdx.x;
    const int lane = tid & 63;
    const int wave = tid >> 6;
    const int wr = wave >> 1, wc = wave & 1;
    const int q = lane >> 4, li = lane & 15;
    const int r0 = blockIdx.x * 128;
    const int n0 = blockIdx.y * 128;

    f32x4 acc[4][4];
#pragma unroll
    for (int i = 0; i < 4; ++i)
#pragma unroll
        for (int j = 0; j < 4; ++j) acc[i][j] = (f32x4){0.f, 0.f, 0.f, 0.f};

    for (int kk = 0; kk < 256; kk += 64) {
        __syncthreads();
#pragma unroll
        for (int j = 0; j < 4; ++j) {
            int g = j * 256 + tid;
            int m = g >> 3, kg = g & 7;
            int mf = m >> 4, mr = m & 15;
            int row = r0 + m;
            float4 v0 = make_float4(0.f, 0.f, 0.f, 0.f), v1 = v0;
            if (row < Nrows) {
                const float* p = A + (size_t)row * 256 + kk + kg * 8;
                v0 = *reinterpret_cast<const float4*>(p);
                v1 = *reinterpret_cast<const float4*>(p + 4);
            }
            union { bf16x8 v; ushort u[8]; } pk;
            pk.u[0] = f2bf(v0.x); pk.u[1] = f2bf(v0.y);
            pk.u[2] = f2bf(v0.z); pk.u[3] = f2bf(v0.w);
            pk.u[4] = f2bf(v1.x); pk.u[5] = f2bf(v1.y);
            pk.u[6] = f2bf(v1.z); pk.u[7] = f2bf(v1.w);
            *reinterpret_cast<bf16x8*>(&As[((mf * 8 + kg) * 16 + (mr ^ kg)) * 8]) = pk.v;
        }
#pragma unroll
        for (int j = 0; j < 4; ++j) {
            int g = j * 256 + tid;
            int n = g >> 3, kg = g & 7;
            int nf = n >> 4, nr = n & 15;
            bf16x8 v = *reinterpret_cast<const bf16x8*>(Bt + (size_t)(n0 + n) * 256 + kk + kg * 8);
            *reinterpret_cast<bf16x8*>(&Bs[((nf * 8 + kg) * 16 + (nr ^ kg)) * 8]) = v;
        }
        __syncthreads();
#pragma unroll
        for (int t = 0; t < 2; ++t) {
            const int kc = t * 4 + q;
            bf16x8 af[4], bfv[4];
#pragma unroll
            for (int f = 0; f < 4; ++f) {
                af[f] = *reinterpret_cast<const bf16x8*>(
                    &As[(((wr * 4 + f) * 8 + kc) * 16 + (li ^ kc)) * 8]);
                bfv[f] = *reinterpret_cast<const bf16x8*>(
                    &Bs[(((wc * 4 + f) * 8 + kc) * 16 + (li ^ kc)) * 8]);
            }
#pragma unroll
            for (int f = 0; f < 4; ++f)
#pragma unroll
                for (int f2 = 0; f2 < 4; ++f2)
                    acc[f][f2] =
                        __builtin_amdgcn_mfma_f32_16x16x32_bf16(af[f], bfv[f2], acc[f][f2], 0, 0, 0);
        }
    }

    // ---- fused epilogue ----
    if constexpr (MCOLS == 256) {
        const int hblk = (n0 >> 6) + wc;  // this wave's head (0..3)
        float alv[4], arv[4];
#pragma unroll
        for (int f2 = 0; f2 < 4; ++f2) {
            alv[f2] = al[hblk * 64 + f2 * 16 + li];
            arv[f2] = ar[hblk * 64 + f2 * 16 + li];
        }
#pragma unroll
        for (int f = 0; f < 4; ++f) {
#pragma unroll
            for (int r = 0; r < 4; ++r) {
                int row = r0 + wr * 64 + f * 16 + q * 4 + r;  // uniform across li-group
                bool ok = row < Nrows;
                float elp = 0.f, erp = 0.f;
#pragma unroll
                for (int f2 = 0; f2 < 4; ++f2) {
                    float v = acc[f][f2][r];
                    elp = fmaf(v, alv[f2], elp);
                    erp = fmaf(v, arv[f2], erp);
                    if (ok) featb[(size_t)row * 256 + (f2 * 16 + li) * 4 + hblk] = f2bf(v);
                }
#pragma unroll
                for (int o = 1; o < 16; o <<= 1) {
                    elp += __shfl_xor(elp, o);
                    erp += __shfl_xor(erp, o);
                }
                if (ok && li == 0) {
                    el[row * 4 + hblk] = elp;
                    er[row * 4 + hblk] = erp;
                }
            }
        }
    } else {  // MCOLS == 128, layer 2
        if (wc == 0) {  // head half: featb + el/er
            float alv[4], arv[4];
#pragma unroll
            for (int f2 = 0; f2 < 4; ++f2) {
                alv[f2] = al[f2 * 16 + li];
                arv[f2] = ar[f2 * 16 + li];
            }
#pragma unroll
            for (int f = 0; f < 4; ++f) {
#pragma unroll
                for (int r = 0; r < 4; ++r) {
                    int row = r0 + wr * 64 + f * 16 + q * 4 + r;
                    bool ok = row < Nrows;
                    float elp = 0.f, erp = 0.f;
#pragma unroll
                    for (int f2 = 0; f2 < 4; ++f2) {
                        float v = acc[f][f2][r];
                        elp = fmaf(v, alv[f2], elp);
                        erp = fmaf(v, arv[f2], erp);
                        if (ok) featb[(size_t)row * 64 + f2 * 16 + li] = f2bf(v);
                    }
#pragma unroll
                    for (int o = 1; o < 16; o <<= 1) {
                        elp += __shfl_xor(elp, o);
                        erp += __shfl_xor(erp, o);
                    }
                    if (ok && li == 0) {
                        el[row] = elp;
                        er[row] = erp;
                    }
                }
            }
        } else {  // residual half: fp32 write
#pragma unroll
            for (int f = 0; f < 4; ++f) {
#pragma unroll
                for (int r = 0; r < 4; ++r) {
                    int row = r0 + wr * 64 + f * 16 + q * 4 + r;
                    if (row < Nrows) {
#pragma unroll
                        for (int f2 = 0; f2 < 4; ++f2)
                            resid[(size_t)row * 64 + f2 * 16 + li] = acc[f][f2][r];
                    }
                }
            }
        }
    }
}

// ---------------- per-dst-node softmax aggregation (one wave per node, no max pass) ----------------
template <int H, int RES, bool ACT>
__global__ __launch_bounds__(256) void agg_kernel(
    const ushort* __restrict__ featb, int fstride, const float* __restrict__ el,
    const float* __restrict__ er, const int* __restrict__ row_start,
    const int* __restrict__ csr_src, const float* __restrict__ resbuf, int rstride,
    const float* __restrict__ bias, float* __restrict__ out, int ostride, int Nn) {
    __shared__ float wbuf[4][64 * H];
    __shared__ int obuf[4][64];
    const int wv = threadIdx.x >> 6, lane = threadIdx.x & 63;
    int node = blockIdx.x * 4 + wv;
    if (node >= Nn) return;

    int begin = row_start[node], end = row_start[node + 1];

    float ern[H];
    if constexpr (H == 4) {
        float4 e4 = *(reinterpret_cast<const float4*>(er) + node);
        ern[0] = e4.x; ern[1] = e4.y; ern[2] = e4.z; ern[3] = e4.w;
    } else {
        ern[0] = er[node];
    }

    float denom[H], acc[H];
#pragma unroll
    for (int h = 0; h < H; ++h) { denom[h] = 0.f; acc[h] = 0.f; }

    for (int c = begin; c < end; c += 64) {
        int nE = min(64, end - c);
        int s = (lane < nE) ? csr_src[c + lane] : 0;
        float w[H];
        if constexpr (H == 4) {
            float4 e4 = *(reinterpret_cast<const float4*>(el) + s);
            w[0] = __expf(leaky(e4.x + ern[0]));
            w[1] = __expf(leaky(e4.y + ern[1]));
            w[2] = __expf(leaky(e4.z + ern[2]));
            w[3] = __expf(leaky(e4.w + ern[3]));
        } else {
            w[0] = __expf(leaky(el[s] + ern[0]));
        }
        if (lane >= nE) {
#pragma unroll
            for (int h = 0; h < H; ++h) w[h] = 0.f;
        }
#pragma unroll
        for (int h = 0; h < H; ++h) denom[h] += w[h];
        obuf[wv][lane] = s * fstride;
        if constexpr (H == 4)
            *reinterpret_cast<float4*>(&wbuf[wv][lane * 4]) = make_float4(w[0], w[1], w[2], w[3]);
        else
            wbuf[wv][lane] = w[0];
        __asm__ volatile("s_waitcnt lgkmcnt(0)" ::: "memory");

#pragma unroll 2
        for (int e = 0; e < nE; ++e) {
            int off = obuf[wv][e];
            if constexpr (H == 4) {
                float4 we = *reinterpret_cast<const float4*>(&wbuf[wv][e * 4]);
                ushort4 f4 = *reinterpret_cast<const ushort4*>(featb + off + lane * 4);
                acc[0] = fmaf(we.x, bf2f(f4.x), acc[0]);
                acc[1] = fmaf(we.y, bf2f(f4.y), acc[1]);
                acc[2] = fmaf(we.z, bf2f(f4.z), acc[2]);
                acc[3] = fmaf(we.w, bf2f(f4.w), acc[3]);
            } else {
                float we = wbuf[wv][e];
                acc[0] = fmaf(we, bf2f(featb[off + lane]), acc[0]);
            }
        }
        __asm__ volatile("" ::: "memory");
    }

#pragma unroll
    for (int h = 0; h < H; ++h)
        for (int o = 32; o; o >>= 1) denom[h] += __shfl_xor(denom[h], o);

#pragma unroll
    for (int h = 0; h < H; ++h) {
        float o = (end > begin) ? acc[h] / denom[h] : 0.f;
        if constexpr (RES == 1) o += resbuf[(size_t)node * rstride + h * 64 + lane];
        if constexpr (RES == 2) o += resbuf[(size_t)node * rstride + lane];
        o += bias[h * 64 + lane];
        if constexpr (ACT) o = (o > 0.f) ? o : (__expf(o) - 1.f);
        out[(size_t)node * ostride + h * 64 + lane] = o;
    }
}

// ---------------- launch ----------------
extern "C" void kernel_launch(void* const* d_in, const int* in_sizes, int n_in, void* d_out,
                              int out_size, void* d_ws, size_t ws_size, hipStream_t stream) {
    const float* x   = (const float*)d_in[0];
    const int* src   = (const int*)d_in[1];
    const int* dst   = (const int*)d_in[2];
    const float* W0  = (const float*)d_in[3];
    const float* al0 = (const float*)d_in[4];
    const float* ar0 = (const float*)d_in[5];
    const float* b0  = (const float*)d_in[6];
    const float* W1  = (const float*)d_in[7];
    const float* al1 = (const float*)d_in[8];
    const float* ar1 = (const float*)d_in[9];
    const float* b1  = (const float*)d_in[10];
    const float* W2  = (const float*)d_in[11];
    const float* al2 = (const float*)d_in[12];
    const float* ar2 = (const float*)d_in[13];
    const float* b2  = (const float*)d_in[14];
    const float* Wr2 = (const float*)d_in[15];
    float* out = (float*)d_out;

    char* w = (char*)d_ws;
    size_t off = 0;
    auto alloc = [&](size_t bytes) -> char* {
        char* p = w + off;
        off += (bytes + 255) & ~(size_t)255;
        return p;
    };
    float* hbuf     = (float*)alloc((size_t)NNODES * 256 * 4);
    ushort* featb   = (ushort*)alloc((size_t)NNODES * 256 * 2);
    float* resid    = (float*)alloc((size_t)NNODES * 64 * 4);
    float* el       = (float*)alloc((size_t)NNODES * 4 * 4);
    float* er       = (float*)alloc((size_t)NNODES * 4 * 4);
    ushort* Bt0     = (ushort*)alloc(65536 * 2);
    ushort* Bt1     = (ushort*)alloc(65536 * 2);
    ushort* Bt2     = (ushort*)alloc(32768 * 2);
    int* counts     = (int*)alloc((size_t)NNODES * 4 * 2);
    int* cursor     = counts + NNODES;
    int* row_start  = (int*)alloc((size_t)(NNODES + 1) * 4);
    int* bsum       = (int*)alloc(64 * 4);
    int* csr_src    = (int*)alloc((size_t)NEDGES * 4);

    hipMemsetAsync(counts, 0, (size_t)NNODES * 4 * 2, stream);

    const int EB = (NEDGES + 255) / 256;
    const int NB4 = (NNODES + 3) / 4;
    const int NBM = (NNODES + 127) / 128;
    const int NSB = (NNODES + 1023) / 1024;

    hist_kernel<<<EB, 256, 0, stream>>>(dst, counts);
    scan_partial<<<NSB, 256, 0, stream>>>(counts, bsum, NNODES);
    scan_final<<<NSB, 256, 0, stream>>>(counts, bsum, row_start, NNODES, NSB);
    scatter_kernel<<<EB, 256, 0, stream>>>(src, dst, row_start, cursor, csr_src);
    pack_kernel<<<640, 256, 0, stream>>>(W0, W1, W2, Wr2, Bt0, Bt1, Bt2);

    // ---- layer 0: x -> (featb, el, er) -> hbuf (ELU, no residual)
    gemm_mfma<256><<<dim3(NBM, 2), 256, 0, stream>>>(x, Bt0, al0, ar0, featb, el, er,
                                                     nullptr, NNODES);
    agg_kernel<4, 0, true><<<NB4, 256, 0, stream>>>(featb, 256, el, er, row_start, csr_src,
                                                    nullptr, 0, b0, hbuf, 256, NNODES);
    // ---- layer 1: hbuf -> (featb, el, er) -> hbuf (ELU, identity residual, in-place)
    gemm_mfma<256><<<dim3(NBM, 2), 256, 0, stream>>>(hbuf, Bt1, al1, ar1, featb, el, er,
                                                     nullptr, NNODES);
    agg_kernel<4, 1, true><<<NB4, 256, 0, stream>>>(featb, 256, el, er, row_start, csr_src,
                                                    hbuf, 256, b1, hbuf, 256, NNODES);
    // ---- layer 2: hbuf @ [W2|res_w2]^T -> (featb[n][64], el, er, resid) -> out
    gemm_mfma<128><<<dim3(NBM, 1), 256, 0, stream>>>(hbuf, Bt2, al2, ar2, featb, el, er,
                                                     resid, NNODES);
    agg_kernel<1, 2, false><<<NB4, 256, 0, stream>>>(featb, 64, el, er, row_start, csr_src,
                                                     resid, 64, b2, out, 64, NNODES);
}

// Round 6
// 457.343 us; speedup vs baseline: 2.1889x; 1.0325x over previous
//
#include <hip/hip_runtime.h>
#include <math.h>

#define NNODES 50000
#define NEDGES 800000

__device__ __forceinline__ float leaky(float x) { return x > 0.f ? x : 0.2f * x; }

__device__ __forceinline__ ushort f2bf(float f) {
    unsigned u = __float_as_uint(f);
    return (ushort)((u + 0x7fffu + ((u >> 16) & 1u)) >> 16);  // RNE
}
__device__ __forceinline__ float bf2f(ushort u) {
    return __uint_as_float((unsigned)u << 16);
}

// ---------------- CSR build ----------------
__global__ void hist_kernel(const int* __restrict__ dst, int* __restrict__ counts) {
    int e = blockIdx.x * 256 + threadIdx.x;
    if (e < NEDGES) atomicAdd(&counts[dst[e]], 1);
}

__global__ __launch_bounds__(256) void scan_partial(const int* __restrict__ counts,
                                                    int* __restrict__ bsum, int Nn) {
    int b = blockIdx.x, t = threadIdx.x;
    int base = b * 1024;
    int v = 0;
#pragma unroll
    for (int i = 0; i < 4; ++i) {
        int idx = base + t + 256 * i;
        if (idx < Nn) v += counts[idx];
    }
    for (int o = 32; o; o >>= 1) v += __shfl_xor(v, o);
    __shared__ int ws[4];
    if ((t & 63) == 0) ws[t >> 6] = v;
    __syncthreads();
    if (t == 0) bsum[b] = ws[0] + ws[1] + ws[2] + ws[3];
}

__global__ __launch_bounds__(256) void scan_final(const int* __restrict__ counts,
                                                  const int* __restrict__ bsum,
                                                  int* __restrict__ row_start, int Nn, int nB) {
    __shared__ int off_s;
    __shared__ int tsum[256];
    int b = blockIdx.x, t = threadIdx.x;
    if (t == 0) {
        int o = 0;
        for (int i = 0; i < b; ++i) o += bsum[i];
        off_s = o;
    }
    int base = b * 1024 + t * 4;
    int c0 = 0, c1 = 0, c2 = 0, c3 = 0;
    if (base + 3 < Nn) {
        int4 c = *reinterpret_cast<const int4*>(counts + base);
        c0 = c.x; c1 = c.y; c2 = c.z; c3 = c.w;
    } else {
        if (base + 0 < Nn) c0 = counts[base + 0];
        if (base + 1 < Nn) c1 = counts[base + 1];
        if (base + 2 < Nn) c2 = counts[base + 2];
        if (base + 3 < Nn) c3 = counts[base + 3];
    }
    int s0 = c0, s1 = s0 + c1, s2 = s1 + c2, s3 = s2 + c3;
    tsum[t] = s3;
    __syncthreads();
    for (int o = 1; o < 256; o <<= 1) {
        int u = (t >= o) ? tsum[t - o] : 0;
        __syncthreads();
        tsum[t] += u;
        __syncthreads();
    }
    int o = off_s + tsum[t] - s3;
    if (base + 3 < Nn) {
        *reinterpret_cast<int4*>(row_start + base) = make_int4(o, o + s0, o + s1, o + s2);
    } else {
        if (base + 0 < Nn) row_start[base + 0] = o;
        if (base + 1 < Nn) row_start[base + 1] = o + s0;
        if (base + 2 < Nn) row_start[base + 2] = o + s1;
        if (base + 3 < Nn) row_start[base + 3] = o + s2;
    }
    if (b == nB - 1 && t == 255) row_start[Nn] = off_s + tsum[255];
}

__global__ void scatter_kernel(const int* __restrict__ src, const int* __restrict__ dst,
                               const int* __restrict__ row_start, int* __restrict__ cursor,
                               int* __restrict__ csr_src) {
    int e = blockIdx.x * 256 + threadIdx.x;
    if (e < NEDGES) {
        int d = dst[e];
        int pos = row_start[d] + atomicAdd(&cursor[d], 1);
        csr_src[pos] = src[e];
    }
}

// ---------------- pack weights: Bt[n][k] bf16 (transposed + converted) ----------------
__global__ void pack_kernel(const float* __restrict__ W0, const float* __restrict__ W1,
                            const float* __restrict__ W2, const float* __restrict__ Wr,
                            ushort* __restrict__ Bt0, ushort* __restrict__ Bt1,
                            ushort* __restrict__ Bt2) {
    int idx = blockIdx.x * 256 + threadIdx.x;  // 0..163839
    if (idx < 65536) {
        int n = idx >> 8, k = idx & 255;
        Bt0[idx] = f2bf(W0[k * 256 + n]);
    } else if (idx < 131072) {
        int j = idx - 65536;
        int n = j >> 8, k = j & 255;
        Bt1[j] = f2bf(W1[k * 256 + n]);
    } else {
        int j = idx - 131072;
        int n = j >> 8, k = j & 255;
        Bt2[j] = f2bf(n < 64 ? W2[k * 64 + n] : Wr[k * 64 + (n - 64)]);
    }
}

// ---- MFMA GEMM fused with el/er + bf16 repack epilogue ----
template <int MCOLS>
__global__ __launch_bounds__(256) void gemm_mfma(const float* __restrict__ A,
                                                 const ushort* __restrict__ Bt,
                                                 const float* __restrict__ al,
                                                 const float* __restrict__ ar,
                                                 ushort* __restrict__ featb,
                                                 float* __restrict__ el, float* __restrict__ er,
                                                 float* __restrict__ resid, int Nrows) {
    using bf16x8 = __attribute__((ext_vector_type(8))) short;
    using f32x4 = __attribute__((ext_vector_type(4))) float;
    __shared__ ushort As[8192];  // 128 rows x 64 k, bf16
    __shared__ ushort Bs[8192];
    const int tid = threadIdx.x;
    const int lane = tid & 63;
    const int wave = tid >> 6;
    const int wr = wave >> 1, wc = wave & 1;
    const int q = lane >> 4, li = lane & 15;
    const int r0 = blockIdx.x * 128;
    const int n0 = blockIdx.y * 128;

    f32x4 acc[4][4];
#pragma unroll
    for (int i = 0; i < 4; ++i)
#pragma unroll
        for (int j = 0; j < 4; ++j) acc[i][j] = (f32x4){0.f, 0.f, 0.f, 0.f};

    for (int kk = 0; kk < 256; kk += 64) {
        __syncthreads();
#pragma unroll
        for (int j = 0; j < 4; ++j) {
            int g = j * 256 + tid;
            int m = g >> 3, kg = g & 7;
            int mf = m >> 4, mr = m & 15;
            int row = r0 + m;
            float4 v0 = make_float4(0.f, 0.f, 0.f, 0.f), v1 = v0;
            if (row < Nrows) {
                const float* p = A + (size_t)row * 256 + kk + kg * 8;
                v0 = *reinterpret_cast<const float4*>(p);
                v1 = *reinterpret_cast<const float4*>(p + 4);
            }
            union { bf16x8 v; ushort u[8]; } pk;
            pk.u[0] = f2bf(v0.x); pk.u[1] = f2bf(v0.y);
            pk.u[2] = f2bf(v0.z); pk.u[3] = f2bf(v0.w);
            pk.u[4] = f2bf(v1.x); pk.u[5] = f2bf(v1.y);
            pk.u[6] = f2bf(v1.z); pk.u[7] = f2bf(v1.w);
            *reinterpret_cast<bf16x8*>(&As[((mf * 8 + kg) * 16 + (mr ^ kg)) * 8]) = pk.v;
        }
#pragma unroll
        for (int j = 0; j < 4; ++j) {
            int g = j * 256 + tid;
            int n = g >> 3, kg = g & 7;
            int nf = n >> 4, nr = n & 15;
            bf16x8 v = *reinterpret_cast<const bf16x8*>(Bt + (size_t)(n0 + n) * 256 + kk + kg * 8);
            *reinterpret_cast<bf16x8*>(&Bs[((nf * 8 + kg) * 16 + (nr ^ kg)) * 8]) = v;
        }
        __syncthreads();
#pragma unroll
        for (int t = 0; t < 2; ++t) {
            const int kc = t * 4 + q;
            bf16x8 af[4], bfv[4];
#pragma unroll
            for (int f = 0; f < 4; ++f) {
                af[f] = *reinterpret_cast<const bf16x8*>(
                    &As[(((wr * 4 + f) * 8 + kc) * 16 + (li ^ kc)) * 8]);
                bfv[f] = *reinterpret_cast<const bf16x8*>(
                    &Bs[(((wc * 4 + f) * 8 + kc) * 16 + (li ^ kc)) * 8]);
            }
#pragma unroll
            for (int f = 0; f < 4; ++f)
#pragma unroll
                for (int f2 = 0; f2 < 4; ++f2)
                    acc[f][f2] =
                        __builtin_amdgcn_mfma_f32_16x16x32_bf16(af[f], bfv[f2], acc[f][f2], 0, 0, 0);
        }
    }

    // ---- fused epilogue ----
    if constexpr (MCOLS == 256) {
        const int hblk = (n0 >> 6) + wc;  // this wave's head (0..3)
        float alv[4], arv[4];
#pragma unroll
        for (int f2 = 0; f2 < 4; ++f2) {
            alv[f2] = al[hblk * 64 + f2 * 16 + li];
            arv[f2] = ar[hblk * 64 + f2 * 16 + li];
        }
#pragma unroll
        for (int f = 0; f < 4; ++f) {
#pragma unroll
            for (int r = 0; r < 4; ++r) {
                int row = r0 + wr * 64 + f * 16 + q * 4 + r;
                bool ok = row < Nrows;
                float elp = 0.f, erp = 0.f;
#pragma unroll
                for (int f2 = 0; f2 < 4; ++f2) {
                    float v = acc[f][f2][r];
                    elp = fmaf(v, alv[f2], elp);
                    erp = fmaf(v, arv[f2], erp);
                    if (ok) featb[(size_t)row * 256 + (f2 * 16 + li) * 4 + hblk] = f2bf(v);
                }
#pragma unroll
                for (int o = 1; o < 16; o <<= 1) {
                    elp += __shfl_xor(elp, o);
                    erp += __shfl_xor(erp, o);
                }
                if (ok && li == 0) {
                    el[row * 4 + hblk] = elp;
                    er[row * 4 + hblk] = erp;
                }
            }
        }
    } else {  // MCOLS == 128, layer 2
        if (wc == 0) {  // head half: featb + el/er
            float alv[4], arv[4];
#pragma unroll
            for (int f2 = 0; f2 < 4; ++f2) {
                alv[f2] = al[f2 * 16 + li];
                arv[f2] = ar[f2 * 16 + li];
            }
#pragma unroll
            for (int f = 0; f < 4; ++f) {
#pragma unroll
                for (int r = 0; r < 4; ++r) {
                    int row = r0 + wr * 64 + f * 16 + q * 4 + r;
                    bool ok = row < Nrows;
                    float elp = 0.f, erp = 0.f;
#pragma unroll
                    for (int f2 = 0; f2 < 4; ++f2) {
                        float v = acc[f][f2][r];
                        elp = fmaf(v, alv[f2], elp);
                        erp = fmaf(v, arv[f2], erp);
                        if (ok) featb[(size_t)row * 64 + f2 * 16 + li] = f2bf(v);
                    }
#pragma unroll
                    for (int o = 1; o < 16; o <<= 1) {
                        elp += __shfl_xor(elp, o);
                        erp += __shfl_xor(erp, o);
                    }
                    if (ok && li == 0) {
                        el[row] = elp;
                        er[row] = erp;
                    }
                }
            }
        } else {  // residual half: fp32 write
#pragma unroll
            for (int f = 0; f < 4; ++f) {
#pragma unroll
                for (int r = 0; r < 4; ++r) {
                    int row = r0 + wr * 64 + f * 16 + q * 4 + r;
                    if (row < Nrows) {
#pragma unroll
                        for (int f2 = 0; f2 < 4; ++f2)
                            resid[(size_t)row * 64 + f2 * 16 + li] = acc[f][f2][r];
                    }
                }
            }
        }
    }
}

// ---------------- agg H=4: 2 edges/iter, 32 lanes x ushort8 (16B) each ----------------
template <int RES, bool ACT>
__global__ __launch_bounds__(256) void agg4_kernel(
    const ushort* __restrict__ featb, const float* __restrict__ el,
    const float* __restrict__ er, const int* __restrict__ row_start,
    const int* __restrict__ csr_src, const float* __restrict__ resbuf,
    const float* __restrict__ bias, float* __restrict__ out, int Nn) {
    using ushort8v = __attribute__((ext_vector_type(8))) unsigned short;
    __shared__ float wbuf[4][256];
    __shared__ int obuf[4][64];
    const int wv = threadIdx.x >> 6, lane = threadIdx.x & 63;
    const int g = lane >> 5, li = lane & 31;
    int node = blockIdx.x * 4 + wv;
    if (node >= Nn) return;

    int begin = row_start[node], end = row_start[node + 1];
    float4 ern = *(reinterpret_cast<const float4*>(er) + node);

    float denom[4] = {0.f, 0.f, 0.f, 0.f};
    float acc[2][4] = {{0.f, 0.f, 0.f, 0.f}, {0.f, 0.f, 0.f, 0.f}};

    for (int c = begin; c < end; c += 64) {
        int nE = min(64, end - c);
        float4 w = make_float4(0.f, 0.f, 0.f, 0.f);
        int s = 0;
        if (lane < nE) {
            s = csr_src[c + lane];
            float4 e4 = *(reinterpret_cast<const float4*>(el) + s);
            w.x = __expf(leaky(e4.x + ern.x));
            w.y = __expf(leaky(e4.y + ern.y));
            w.z = __expf(leaky(e4.z + ern.z));
            w.w = __expf(leaky(e4.w + ern.w));
        }
        denom[0] += w.x; denom[1] += w.y; denom[2] += w.z; denom[3] += w.w;
        obuf[wv][lane] = s * 256;
        *reinterpret_cast<float4*>(&wbuf[wv][lane * 4]) = w;
        __asm__ volatile("s_waitcnt lgkmcnt(0)" ::: "memory");

#pragma unroll 4
        for (int e2 = 0; e2 < nE; e2 += 2) {
            int e = e2 + g;  // half g handles edge e2+g
            float4 we = make_float4(0.f, 0.f, 0.f, 0.f);
            int off = 0;
            if (e < nE) {
                off = obuf[wv][e];
                we = *reinterpret_cast<const float4*>(&wbuf[wv][e * 4]);
            }
            ushort8v v = *reinterpret_cast<const ushort8v*>(featb + off + li * 8);
            acc[0][0] = fmaf(we.x, bf2f(v[0]), acc[0][0]);
            acc[0][1] = fmaf(we.y, bf2f(v[1]), acc[0][1]);
            acc[0][2] = fmaf(we.z, bf2f(v[2]), acc[0][2]);
            acc[0][3] = fmaf(we.w, bf2f(v[3]), acc[0][3]);
            acc[1][0] = fmaf(we.x, bf2f(v[4]), acc[1][0]);
            acc[1][1] = fmaf(we.y, bf2f(v[5]), acc[1][1]);
            acc[1][2] = fmaf(we.z, bf2f(v[6]), acc[1][2]);
            acc[1][3] = fmaf(we.w, bf2f(v[7]), acc[1][3]);
        }
        __asm__ volatile("" ::: "memory");
    }

    // combine the two 32-lane halves; lane l and l+32 hold the same (d,h) pair
#pragma unroll
    for (int j = 0; j < 2; ++j)
#pragma unroll
        for (int h = 0; h < 4; ++h) acc[j][h] += __shfl_xor(acc[j][h], 32);
#pragma unroll
    for (int h = 0; h < 4; ++h)
        for (int o = 32; o; o >>= 1) denom[h] += __shfl_xor(denom[h], o);

    bool has = end > begin;
    // group g writes heads {2g, 2g+1}; lane covers d = li*2 + {0,1}
#pragma unroll
    for (int hh = 0; hh < 2; ++hh) {
        int h = g * 2 + hh;
        float d0 = denom[h];
        float o0 = has ? acc[0][h] / d0 : 0.f;
        float o1 = has ? acc[1][h] / d0 : 0.f;
        int dbase = h * 64 + li * 2;
        if constexpr (RES == 1) {
            float2 rv = *reinterpret_cast<const float2*>(resbuf + (size_t)node * 256 + dbase);
            o0 += rv.x; o1 += rv.y;
        }
        float2 bv = *reinterpret_cast<const float2*>(bias + dbase);
        o0 += bv.x; o1 += bv.y;
        if constexpr (ACT) {
            o0 = o0 > 0.f ? o0 : __expf(o0) - 1.f;
            o1 = o1 > 0.f ? o1 : __expf(o1) - 1.f;
        }
        *reinterpret_cast<float2*>(out + (size_t)node * 256 + dbase) = make_float2(o0, o1);
    }
}

// ---------------- agg H=1 (layer 2): 4 edges/iter, 16 lanes x ushort4 (8B) each ----------------
__global__ __launch_bounds__(256) void agg1_kernel(
    const ushort* __restrict__ featb, const float* __restrict__ el,
    const float* __restrict__ er, const int* __restrict__ row_start,
    const int* __restrict__ csr_src, const float* __restrict__ resbuf,
    const float* __restrict__ bias, float* __restrict__ out, int Nn) {
    __shared__ float wbuf[4][64];
    __shared__ int obuf[4][64];
    const int wv = threadIdx.x >> 6, lane = threadIdx.x & 63;
    const int g = lane >> 4, li = lane & 15;
    int node = blockIdx.x * 4 + wv;
    if (node >= Nn) return;

    int begin = row_start[node], end = row_start[node + 1];
    float ern = er[node];
    float denom = 0.f;
    float acc[4] = {0.f, 0.f, 0.f, 0.f};

    for (int c = begin; c < end; c += 64) {
        int nE = min(64, end - c);
        float w = 0.f;
        int s = 0;
        if (lane < nE) {
            s = csr_src[c + lane];
            w = __expf(leaky(el[s] + ern));
        }
        denom += w;
        obuf[wv][lane] = s * 64;
        wbuf[wv][lane] = w;
        __asm__ volatile("s_waitcnt lgkmcnt(0)" ::: "memory");

#pragma unroll 2
        for (int e4i = 0; e4i < nE; e4i += 4) {
            int e = e4i + g;
            float we = 0.f;
            int off = 0;
            if (e < nE) {
                off = obuf[wv][e];
                we = wbuf[wv][e];
            }
            ushort4 v = *reinterpret_cast<const ushort4*>(featb + off + li * 4);
            acc[0] = fmaf(we, bf2f(v.x), acc[0]);
            acc[1] = fmaf(we, bf2f(v.y), acc[1]);
            acc[2] = fmaf(we, bf2f(v.z), acc[2]);
            acc[3] = fmaf(we, bf2f(v.w), acc[3]);
        }
        __asm__ volatile("" ::: "memory");
    }

#pragma unroll
    for (int j = 0; j < 4; ++j) {
        acc[j] += __shfl_xor(acc[j], 16);
        acc[j] += __shfl_xor(acc[j], 32);
    }
    for (int o = 32; o; o >>= 1) denom += __shfl_xor(denom, o);

    if (g == 0) {
        bool has = end > begin;
        float4 rv = *reinterpret_cast<const float4*>(resbuf + (size_t)node * 64 + li * 4);
        float4 bv = *reinterpret_cast<const float4*>(bias + li * 4);
        float4 o4;
        o4.x = (has ? acc[0] / denom : 0.f) + rv.x + bv.x;
        o4.y = (has ? acc[1] / denom : 0.f) + rv.y + bv.y;
        o4.z = (has ? acc[2] / denom : 0.f) + rv.z + bv.z;
        o4.w = (has ? acc[3] / denom : 0.f) + rv.w + bv.w;
        *reinterpret_cast<float4*>(out + (size_t)node * 64 + li * 4) = o4;
    }
}

// ---------------- launch ----------------
extern "C" void kernel_launch(void* const* d_in, const int* in_sizes, int n_in, void* d_out,
                              int out_size, void* d_ws, size_t ws_size, hipStream_t stream) {
    const float* x   = (const float*)d_in[0];
    const int* src   = (const int*)d_in[1];
    const int* dst   = (const int*)d_in[2];
    const float* W0  = (const float*)d_in[3];
    const float* al0 = (const float*)d_in[4];
    const float* ar0 = (const float*)d_in[5];
    const float* b0  = (const float*)d_in[6];
    const float* W1  = (const float*)d_in[7];
    const float* al1 = (const float*)d_in[8];
    const float* ar1 = (const float*)d_in[9];
    const float* b1  = (const float*)d_in[10];
    const float* W2  = (const float*)d_in[11];
    const float* al2 = (const float*)d_in[12];
    const float* ar2 = (const float*)d_in[13];
    const float* b2  = (const float*)d_in[14];
    const float* Wr2 = (const float*)d_in[15];
    float* out = (float*)d_out;

    char* w = (char*)d_ws;
    size_t off = 0;
    auto alloc = [&](size_t bytes) -> char* {
        char* p = w + off;
        off += (bytes + 255) & ~(size_t)255;
        return p;
    };
    float* hbuf     = (float*)alloc((size_t)NNODES * 256 * 4);
    ushort* featb   = (ushort*)alloc((size_t)NNODES * 256 * 2);
    float* resid    = (float*)alloc((size_t)NNODES * 64 * 4);
    float* el       = (float*)alloc((size_t)NNODES * 4 * 4);
    float* er       = (float*)alloc((size_t)NNODES * 4 * 4);
    ushort* Bt0     = (ushort*)alloc(65536 * 2);
    ushort* Bt1     = (ushort*)alloc(65536 * 2);
    ushort* Bt2     = (ushort*)alloc(32768 * 2);
    int* counts     = (int*)alloc((size_t)NNODES * 4 * 2);
    int* cursor     = counts + NNODES;
    int* row_start  = (int*)alloc((size_t)(NNODES + 1) * 4);
    int* bsum       = (int*)alloc(64 * 4);
    int* csr_src    = (int*)alloc((size_t)NEDGES * 4);

    hipMemsetAsync(counts, 0, (size_t)NNODES * 4 * 2, stream);

    const int EB = (NEDGES + 255) / 256;
    const int NB4 = (NNODES + 3) / 4;
    const int NBM = (NNODES + 127) / 128;
    const int NSB = (NNODES + 1023) / 1024;

    hist_kernel<<<EB, 256, 0, stream>>>(dst, counts);
    scan_partial<<<NSB, 256, 0, stream>>>(counts, bsum, NNODES);
    scan_final<<<NSB, 256, 0, stream>>>(counts, bsum, row_start, NNODES, NSB);
    scatter_kernel<<<EB, 256, 0, stream>>>(src, dst, row_start, cursor, csr_src);
    pack_kernel<<<640, 256, 0, stream>>>(W0, W1, W2, Wr2, Bt0, Bt1, Bt2);

    // ---- layer 0: x -> (featb, el, er) -> hbuf (ELU, no residual)
    gemm_mfma<256><<<dim3(NBM, 2), 256, 0, stream>>>(x, Bt0, al0, ar0, featb, el, er,
                                                     nullptr, NNODES);
    agg4_kernel<0, true><<<NB4, 256, 0, stream>>>(featb, el, er, row_start, csr_src,
                                                  nullptr, b0, hbuf, NNODES);
    // ---- layer 1: hbuf -> (featb, el, er) -> hbuf (ELU, identity residual, in-place)
    gemm_mfma<256><<<dim3(NBM, 2), 256, 0, stream>>>(hbuf, Bt1, al1, ar1, featb, el, er,
                                                     nullptr, NNODES);
    agg4_kernel<1, true><<<NB4, 256, 0, stream>>>(featb, el, er, row_start, csr_src,
                                                  hbuf, b1, hbuf, NNODES);
    // ---- layer 2: hbuf @ [W2|res_w2]^T -> (featb[n][64], el, er, resid) -> out
    gemm_mfma<128><<<dim3(NBM, 1), 256, 0, stream>>>(hbuf, Bt2, al2, ar2, featb, el, er,
                                                     resid, NNODES);
    agg1_kernel<<<NB4, 256, 0, stream>>>(featb, el, er, row_start, csr_src,
                                         resid, b2, out, NNODES);
}

// Round 7
// 446.948 us; speedup vs baseline: 2.2398x; 1.0233x over previous
//
#include <hip/hip_runtime.h>
#include <math.h>

#define NNODES 50000
#define NEDGES 800000
#define NSB 49  // scan blocks: ceil(50000/1024)

__device__ __forceinline__ float leaky(float x) { return x > 0.f ? x : 0.2f * x; }

__device__ __forceinline__ ushort f2bf(float f) {
    unsigned u = __float_as_uint(f);
    return (ushort)((u + 0x7fffu + ((u >> 16) & 1u)) >> 16);  // RNE
}
__device__ __forceinline__ float bf2f(ushort u) {
    return __uint_as_float((unsigned)u << 16);
}

typedef const __attribute__((address_space(1))) void* gptr_t;
typedef __attribute__((address_space(3))) void* lptr_t;

// ---------------- CSR build ----------------
__global__ void hist_kernel(const int* __restrict__ dst, int* __restrict__ counts) {
    int e = blockIdx.x * 256 + threadIdx.x;
    if (e < NEDGES) atomicAdd(&counts[dst[e]], 1);
}

// fused: blocks [0,NSB) = scan_partial; blocks [NSB,NSB+640) = weight pack
__global__ __launch_bounds__(256) void prep_kernel(
    const int* __restrict__ counts, int* __restrict__ bsum, int Nn,
    const float* __restrict__ W0, const float* __restrict__ W1, const float* __restrict__ W2,
    const float* __restrict__ Wr, ushort* __restrict__ Bt0, ushort* __restrict__ Bt1,
    ushort* __restrict__ Bt2) {
    int t = threadIdx.x;
    if (blockIdx.x < NSB) {
        int b = blockIdx.x;
        int base = b * 1024;
        int v = 0;
#pragma unroll
        for (int i = 0; i < 4; ++i) {
            int idx = base + t + 256 * i;
            if (idx < Nn) v += counts[idx];
        }
        for (int o = 32; o; o >>= 1) v += __shfl_xor(v, o);
        __shared__ int ws[4];
        if ((t & 63) == 0) ws[t >> 6] = v;
        __syncthreads();
        if (t == 0) bsum[b] = ws[0] + ws[1] + ws[2] + ws[3];
    } else {
        int idx = (blockIdx.x - NSB) * 256 + t;  // 0..163839
        if (idx < 65536) {
            int n = idx >> 8, k = idx & 255;
            Bt0[idx] = f2bf(W0[k * 256 + n]);
        } else if (idx < 131072) {
            int j = idx - 65536;
            int n = j >> 8, k = j & 255;
            Bt1[j] = f2bf(W1[k * 256 + n]);
        } else {
            int j = idx - 131072;
            int n = j >> 8, k = j & 255;
            Bt2[j] = f2bf(n < 64 ? W2[k * 64 + n] : Wr[k * 64 + (n - 64)]);
        }
    }
}

__global__ __launch_bounds__(256) void scan_final(const int* __restrict__ counts,
                                                  const int* __restrict__ bsum,
                                                  int* __restrict__ row_start, int Nn, int nB) {
    __shared__ int off_s;
    __shared__ int tsum[256];
    int b = blockIdx.x, t = threadIdx.x;
    if (t == 0) {
        int o = 0;
        for (int i = 0; i < b; ++i) o += bsum[i];
        off_s = o;
    }
    int base = b * 1024 + t * 4;
    int c0 = 0, c1 = 0, c2 = 0, c3 = 0;
    if (base + 3 < Nn) {
        int4 c = *reinterpret_cast<const int4*>(counts + base);
        c0 = c.x; c1 = c.y; c2 = c.z; c3 = c.w;
    } else {
        if (base + 0 < Nn) c0 = counts[base + 0];
        if (base + 1 < Nn) c1 = counts[base + 1];
        if (base + 2 < Nn) c2 = counts[base + 2];
        if (base + 3 < Nn) c3 = counts[base + 3];
    }
    int s0 = c0, s1 = s0 + c1, s2 = s1 + c2, s3 = s2 + c3;
    tsum[t] = s3;
    __syncthreads();
    for (int o = 1; o < 256; o <<= 1) {
        int u = (t >= o) ? tsum[t - o] : 0;
        __syncthreads();
        tsum[t] += u;
        __syncthreads();
    }
    int o = off_s + tsum[t] - s3;
    if (base + 3 < Nn) {
        *reinterpret_cast<int4*>(row_start + base) = make_int4(o, o + s0, o + s1, o + s2);
    } else {
        if (base + 0 < Nn) row_start[base + 0] = o;
        if (base + 1 < Nn) row_start[base + 1] = o + s0;
        if (base + 2 < Nn) row_start[base + 2] = o + s1;
        if (base + 3 < Nn) row_start[base + 3] = o + s2;
    }
    if (b == nB - 1 && t == 255) row_start[Nn] = off_s + tsum[255];
}

__global__ void scatter_kernel(const int* __restrict__ src, const int* __restrict__ dst,
                               const int* __restrict__ row_start, int* __restrict__ cursor,
                               int* __restrict__ csr_src) {
    int e = blockIdx.x * 256 + threadIdx.x;
    if (e < NEDGES) {
        int d = dst[e];
        int pos = row_start[d] + atomicAdd(&cursor[d], 1);
        csr_src[pos] = src[e];
    }
}

// ---- MFMA GEMM fused with el/er + bf16 repack epilogue ----
// A is fp32 (ABF16=false, XOR-swizzled VGPR staging) or bf16 row-major
// (ABF16=true, lane-ordered global_load_lds staging). B always bf16 via
// global_load_lds, lane-ordered (no XOR); read multiset per quad is unchanged
// so LDS conflicts stay ~0 (watch SQ_LDS_BANK_CONFLICT).
template <int MCOLS, bool ABF16>
__global__ __launch_bounds__(256) void gemm_mfma(const void* __restrict__ Araw,
                                                 const ushort* __restrict__ Bt,
                                                 const float* __restrict__ al,
                                                 const float* __restrict__ ar,
                                                 ushort* __restrict__ featb,
                                                 float* __restrict__ el, float* __restrict__ er,
                                                 float* __restrict__ resid, int Nrows) {
    using bf16x8 = __attribute__((ext_vector_type(8))) short;
    using f32x4 = __attribute__((ext_vector_type(4))) float;
    __shared__ ushort As[8192];  // 128 rows x 64 k, bf16 (16B chunks)
    __shared__ ushort Bs[8192];
    const float* Af = (const float*)Araw;
    const ushort* Ab = (const ushort*)Araw;
    const int tid = threadIdx.x;
    const int lane = tid & 63;
    const int wave = tid >> 6;
    const int wr = wave >> 1, wc = wave & 1;
    const int q = lane >> 4, li = lane & 15;
    const int r0 = blockIdx.x * 128;
    const int n0 = blockIdx.y * 128;

    f32x4 acc[4][4];
#pragma unroll
    for (int i = 0; i < 4; ++i)
#pragma unroll
        for (int j = 0; j < 4; ++j) acc[i][j] = (f32x4){0.f, 0.f, 0.f, 0.f};

    for (int kk = 0; kk < 256; kk += 64) {
        __syncthreads();
        // ---- stage A ----
        if constexpr (ABF16) {
#pragma unroll
            for (int j = 0; j < 4; ++j) {
                int c = (wave * 4 + j) * 64 + lane;
                int mr = c & 15, kg = (c >> 4) & 7, mf = c >> 7;
                const ushort* gp = Ab + (size_t)(r0 + mf * 16 + mr) * 256 + kk + kg * 8;
                void* lp = (char*)As + (size_t)(wave * 4 + j) * 1024;
                __builtin_amdgcn_global_load_lds((gptr_t)gp, (lptr_t)lp, 16, 0, 0);
            }
        } else {
#pragma unroll
            for (int j = 0; j < 4; ++j) {
                int g = j * 256 + tid;
                int m = g >> 3, kg = g & 7;
                int mf = m >> 4, mr = m & 15;
                int row = r0 + m;
                float4 v0 = make_float4(0.f, 0.f, 0.f, 0.f), v1 = v0;
                if (row < Nrows) {
                    const float* p = Af + (size_t)row * 256 + kk + kg * 8;
                    v0 = *reinterpret_cast<const float4*>(p);
                    v1 = *reinterpret_cast<const float4*>(p + 4);
                }
                union { bf16x8 v; ushort u[8]; } pk;
                pk.u[0] = f2bf(v0.x); pk.u[1] = f2bf(v0.y);
                pk.u[2] = f2bf(v0.z); pk.u[3] = f2bf(v0.w);
                pk.u[4] = f2bf(v1.x); pk.u[5] = f2bf(v1.y);
                pk.u[6] = f2bf(v1.z); pk.u[7] = f2bf(v1.w);
                *reinterpret_cast<bf16x8*>(&As[((mf * 8 + kg) * 16 + (mr ^ kg)) * 8]) = pk.v;
            }
        }
        // ---- stage B (always bf16, lane-ordered DMA) ----
#pragma unroll
        for (int j = 0; j < 4; ++j) {
            int c = (wave * 4 + j) * 64 + lane;
            int nr = c & 15, kg = (c >> 4) & 7, nf = c >> 7;
            const ushort* gp = Bt + (size_t)(n0 + nf * 16 + nr) * 256 + kk + kg * 8;
            void* lp = (char*)Bs + (size_t)(wave * 4 + j) * 1024;
            __builtin_amdgcn_global_load_lds((gptr_t)gp, (lptr_t)lp, 16, 0, 0);
        }
        __syncthreads();
#pragma unroll
        for (int t = 0; t < 2; ++t) {
            const int kc = t * 4 + q;
            bf16x8 af[4], bfv[4];
#pragma unroll
            for (int f = 0; f < 4; ++f) {
                int ai = ABF16 ? li : (li ^ kc);
                af[f] = *reinterpret_cast<const bf16x8*>(
                    &As[(((wr * 4 + f) * 8 + kc) * 16 + ai) * 8]);
                bfv[f] = *reinterpret_cast<const bf16x8*>(
                    &Bs[(((wc * 4 + f) * 8 + kc) * 16 + li) * 8]);
            }
#pragma unroll
            for (int f = 0; f < 4; ++f)
#pragma unroll
                for (int f2 = 0; f2 < 4; ++f2)
                    acc[f][f2] =
                        __builtin_amdgcn_mfma_f32_16x16x32_bf16(af[f], bfv[f2], acc[f][f2], 0, 0, 0);
        }
    }

    // ---- fused epilogue ----
    if constexpr (MCOLS == 256) {
        const int hblk = (n0 >> 6) + wc;  // this wave's head (0..3)
        float alv[4], arv[4];
#pragma unroll
        for (int f2 = 0; f2 < 4; ++f2) {
            alv[f2] = al[hblk * 64 + f2 * 16 + li];
            arv[f2] = ar[hblk * 64 + f2 * 16 + li];
        }
#pragma unroll
        for (int f = 0; f < 4; ++f) {
#pragma unroll
            for (int r = 0; r < 4; ++r) {
                int row = r0 + wr * 64 + f * 16 + q * 4 + r;
                bool ok = row < Nrows;
                float elp = 0.f, erp = 0.f;
#pragma unroll
                for (int f2 = 0; f2 < 4; ++f2) {
                    float v = acc[f][f2][r];
                    elp = fmaf(v, alv[f2], elp);
                    erp = fmaf(v, arv[f2], erp);
                    if (ok) featb[(size_t)row * 256 + (f2 * 16 + li) * 4 + hblk] = f2bf(v);
                }
#pragma unroll
                for (int o = 1; o < 16; o <<= 1) {
                    elp += __shfl_xor(elp, o);
                    erp += __shfl_xor(erp, o);
                }
                if (ok && li == 0) {
                    el[row * 4 + hblk] = elp;
                    er[row * 4 + hblk] = erp;
                }
            }
        }
    } else {  // MCOLS == 128, layer 2
        if (wc == 0) {  // head half: featb + el/er
            float alv[4], arv[4];
#pragma unroll
            for (int f2 = 0; f2 < 4; ++f2) {
                alv[f2] = al[f2 * 16 + li];
                arv[f2] = ar[f2 * 16 + li];
            }
#pragma unroll
            for (int f = 0; f < 4; ++f) {
#pragma unroll
                for (int r = 0; r < 4; ++r) {
                    int row = r0 + wr * 64 + f * 16 + q * 4 + r;
                    bool ok = row < Nrows;
                    float elp = 0.f, erp = 0.f;
#pragma unroll
                    for (int f2 = 0; f2 < 4; ++f2) {
                        float v = acc[f][f2][r];
                        elp = fmaf(v, alv[f2], elp);
                        erp = fmaf(v, arv[f2], erp);
                        if (ok) featb[(size_t)row * 64 + f2 * 16 + li] = f2bf(v);
                    }
#pragma unroll
                    for (int o = 1; o < 16; o <<= 1) {
                        elp += __shfl_xor(elp, o);
                        erp += __shfl_xor(erp, o);
                    }
                    if (ok && li == 0) {
                        el[row] = elp;
                        er[row] = erp;
                    }
                }
            }
        } else {  // residual half: fp32 write
#pragma unroll
            for (int f = 0; f < 4; ++f) {
#pragma unroll
                for (int r = 0; r < 4; ++r) {
                    int row = r0 + wr * 64 + f * 16 + q * 4 + r;
                    if (row < Nrows) {
#pragma unroll
                        for (int f2 = 0; f2 < 4; ++f2)
                            resid[(size_t)row * 64 + f2 * 16 + li] = acc[f][f2][r];
                    }
                }
            }
        }
    }
}

// ---------------- agg H=4: 2 edges/iter, 32 lanes x ushort8 (16B) each ----------------
// out/resbuf are bf16 (hbuf); RES: 0 none, 1 identity bf16.
template <int RES, bool ACT>
__global__ __launch_bounds__(256) void agg4_kernel(
    const ushort* __restrict__ featb, const float* __restrict__ el,
    const float* __restrict__ er, const int* __restrict__ row_start,
    const int* __restrict__ csr_src, const ushort* __restrict__ resbuf,
    const float* __restrict__ bias, ushort* __restrict__ out, int Nn) {
    using ushort8v = __attribute__((ext_vector_type(8))) unsigned short;
    __shared__ float wbuf[4][256];
    __shared__ int obuf[4][64];
    const int wv = threadIdx.x >> 6, lane = threadIdx.x & 63;
    const int g = lane >> 5, li = lane & 31;
    int node = blockIdx.x * 4 + wv;
    if (node >= Nn) return;

    int begin = row_start[node], end = row_start[node + 1];
    float4 ern = *(reinterpret_cast<const float4*>(er) + node);

    float denom[4] = {0.f, 0.f, 0.f, 0.f};
    float acc[2][4] = {{0.f, 0.f, 0.f, 0.f}, {0.f, 0.f, 0.f, 0.f}};

    for (int c = begin; c < end; c += 64) {
        int nE = min(64, end - c);
        float4 w = make_float4(0.f, 0.f, 0.f, 0.f);
        int s = 0;
        if (lane < nE) {
            s = csr_src[c + lane];
            float4 e4 = *(reinterpret_cast<const float4*>(el) + s);
            w.x = __expf(leaky(e4.x + ern.x));
            w.y = __expf(leaky(e4.y + ern.y));
            w.z = __expf(leaky(e4.z + ern.z));
            w.w = __expf(leaky(e4.w + ern.w));
        }
        denom[0] += w.x; denom[1] += w.y; denom[2] += w.z; denom[3] += w.w;
        obuf[wv][lane] = s * 256;
        *reinterpret_cast<float4*>(&wbuf[wv][lane * 4]) = w;
        __asm__ volatile("s_waitcnt lgkmcnt(0)" ::: "memory");

#pragma unroll 4
        for (int e2 = 0; e2 < nE; e2 += 2) {
            int e = e2 + g;  // half g handles edge e2+g
            float4 we = make_float4(0.f, 0.f, 0.f, 0.f);
            int off = 0;
            if (e < nE) {
                off = obuf[wv][e];
                we = *reinterpret_cast<const float4*>(&wbuf[wv][e * 4]);
            }
            ushort8v v = *reinterpret_cast<const ushort8v*>(featb + off + li * 8);
            acc[0][0] = fmaf(we.x, bf2f(v[0]), acc[0][0]);
            acc[0][1] = fmaf(we.y, bf2f(v[1]), acc[0][1]);
            acc[0][2] = fmaf(we.z, bf2f(v[2]), acc[0][2]);
            acc[0][3] = fmaf(we.w, bf2f(v[3]), acc[0][3]);
            acc[1][0] = fmaf(we.x, bf2f(v[4]), acc[1][0]);
            acc[1][1] = fmaf(we.y, bf2f(v[5]), acc[1][1]);
            acc[1][2] = fmaf(we.z, bf2f(v[6]), acc[1][2]);
            acc[1][3] = fmaf(we.w, bf2f(v[7]), acc[1][3]);
        }
        __asm__ volatile("" ::: "memory");
    }

#pragma unroll
    for (int j = 0; j < 2; ++j)
#pragma unroll
        for (int h = 0; h < 4; ++h) acc[j][h] += __shfl_xor(acc[j][h], 32);
#pragma unroll
    for (int h = 0; h < 4; ++h)
        for (int o = 32; o; o >>= 1) denom[h] += __shfl_xor(denom[h], o);

    bool has = end > begin;
#pragma unroll
    for (int hh = 0; hh < 2; ++hh) {
        int h = g * 2 + hh;
        float d0 = denom[h];
        float o0 = has ? acc[0][h] / d0 : 0.f;
        float o1 = has ? acc[1][h] / d0 : 0.f;
        int dbase = h * 64 + li * 2;
        if constexpr (RES == 1) {
            unsigned rv = *reinterpret_cast<const unsigned*>(resbuf + (size_t)node * 256 + dbase);
            o0 += bf2f((ushort)(rv & 0xffffu));
            o1 += bf2f((ushort)(rv >> 16));
        }
        float2 bv = *reinterpret_cast<const float2*>(bias + dbase);
        o0 += bv.x; o1 += bv.y;
        if constexpr (ACT) {
            o0 = o0 > 0.f ? o0 : __expf(o0) - 1.f;
            o1 = o1 > 0.f ? o1 : __expf(o1) - 1.f;
        }
        unsigned pk = (unsigned)f2bf(o0) | ((unsigned)f2bf(o1) << 16);
        *reinterpret_cast<unsigned*>(out + (size_t)node * 256 + dbase) = pk;
    }
}

// ---------------- agg H=1 (layer 2): 4 edges/iter, 16 lanes x ushort4 (8B) each ----------------
__global__ __launch_bounds__(256) void agg1_kernel(
    const ushort* __restrict__ featb, const float* __restrict__ el,
    const float* __restrict__ er, const int* __restrict__ row_start,
    const int* __restrict__ csr_src, const float* __restrict__ resbuf,
    const float* __restrict__ bias, float* __restrict__ out, int Nn) {
    __shared__ float wbuf[4][64];
    __shared__ int obuf[4][64];
    const int wv = threadIdx.x >> 6, lane = threadIdx.x & 63;
    const int g = lane >> 4, li = lane & 15;
    int node = blockIdx.x * 4 + wv;
    if (node >= Nn) return;

    int begin = row_start[node], end = row_start[node + 1];
    float ern = er[node];
    float denom = 0.f;
    float acc[4] = {0.f, 0.f, 0.f, 0.f};

    for (int c = begin; c < end; c += 64) {
        int nE = min(64, end - c);
        float w = 0.f;
        int s = 0;
        if (lane < nE) {
            s = csr_src[c + lane];
            w = __expf(leaky(el[s] + ern));
        }
        denom += w;
        obuf[wv][lane] = s * 64;
        wbuf[wv][lane] = w;
        __asm__ volatile("s_waitcnt lgkmcnt(0)" ::: "memory");

#pragma unroll 2
        for (int e4i = 0; e4i < nE; e4i += 4) {
            int e = e4i + g;
            float we = 0.f;
            int off = 0;
            if (e < nE) {
                off = obuf[wv][e];
                we = wbuf[wv][e];
            }
            ushort4 v = *reinterpret_cast<const ushort4*>(featb + off + li * 4);
            acc[0] = fmaf(we, bf2f(v.x), acc[0]);
            acc[1] = fmaf(we, bf2f(v.y), acc[1]);
            acc[2] = fmaf(we, bf2f(v.z), acc[2]);
            acc[3] = fmaf(we, bf2f(v.w), acc[3]);
        }
        __asm__ volatile("" ::: "memory");
    }

#pragma unroll
    for (int j = 0; j < 4; ++j) {
        acc[j] += __shfl_xor(acc[j], 16);
        acc[j] += __shfl_xor(acc[j], 32);
    }
    for (int o = 32; o; o >>= 1) denom += __shfl_xor(denom, o);

    if (g == 0) {
        bool has = end > begin;
        float4 rv = *reinterpret_cast<const float4*>(resbuf + (size_t)node * 64 + li * 4);
        float4 bv = *reinterpret_cast<const float4*>(bias + li * 4);
        float4 o4;
        o4.x = (has ? acc[0] / denom : 0.f) + rv.x + bv.x;
        o4.y = (has ? acc[1] / denom : 0.f) + rv.y + bv.y;
        o4.z = (has ? acc[2] / denom : 0.f) + rv.z + bv.z;
        o4.w = (has ? acc[3] / denom : 0.f) + rv.w + bv.w;
        *reinterpret_cast<float4*>(out + (size_t)node * 64 + li * 4) = o4;
    }
}

// ---------------- launch ----------------
extern "C" void kernel_launch(void* const* d_in, const int* in_sizes, int n_in, void* d_out,
                              int out_size, void* d_ws, size_t ws_size, hipStream_t stream) {
    const float* x   = (const float*)d_in[0];
    const int* src   = (const int*)d_in[1];
    const int* dst   = (const int*)d_in[2];
    const float* W0  = (const float*)d_in[3];
    const float* al0 = (const float*)d_in[4];
    const float* ar0 = (const float*)d_in[5];
    const float* b0  = (const float*)d_in[6];
    const float* W1  = (const float*)d_in[7];
    const float* al1 = (const float*)d_in[8];
    const float* ar1 = (const float*)d_in[9];
    const float* b1  = (const float*)d_in[10];
    const float* W2  = (const float*)d_in[11];
    const float* al2 = (const float*)d_in[12];
    const float* ar2 = (const float*)d_in[13];
    const float* b2  = (const float*)d_in[14];
    const float* Wr2 = (const float*)d_in[15];
    float* out = (float*)d_out;

    char* w = (char*)d_ws;
    size_t off = 0;
    auto alloc = [&](size_t bytes) -> char* {
        char* p = w + off;
        off += (bytes + 255) & ~(size_t)255;
        return p;
    };
    ushort* hbuf    = (ushort*)alloc((size_t)NNODES * 256 * 2);  // bf16 h0/h1
    ushort* featb   = (ushort*)alloc((size_t)NNODES * 256 * 2);  // bf16 messages
    float* resid    = (float*)alloc((size_t)NNODES * 64 * 4);
    float* el       = (float*)alloc((size_t)NNODES * 4 * 4);
    float* er       = (float*)alloc((size_t)NNODES * 4 * 4);
    ushort* Bt0     = (ushort*)alloc(65536 * 2);
    ushort* Bt1     = (ushort*)alloc(65536 * 2);
    ushort* Bt2     = (ushort*)alloc(32768 * 2);
    int* counts     = (int*)alloc((size_t)NNODES * 4 * 2);
    int* cursor     = counts + NNODES;
    int* row_start  = (int*)alloc((size_t)(NNODES + 1) * 4);
    int* bsum       = (int*)alloc(64 * 4);
    int* csr_src    = (int*)alloc((size_t)NEDGES * 4);

    hipMemsetAsync(counts, 0, (size_t)NNODES * 4 * 2, stream);

    const int EB = (NEDGES + 255) / 256;
    const int NB4 = (NNODES + 3) / 4;
    const int NBM = (NNODES + 127) / 128;

    hist_kernel<<<EB, 256, 0, stream>>>(dst, counts);
    prep_kernel<<<NSB + 640, 256, 0, stream>>>(counts, bsum, NNODES, W0, W1, W2, Wr2,
                                               Bt0, Bt1, Bt2);
    scan_final<<<NSB, 256, 0, stream>>>(counts, bsum, row_start, NNODES, NSB);
    scatter_kernel<<<EB, 256, 0, stream>>>(src, dst, row_start, cursor, csr_src);

    // ---- layer 0: x (fp32) -> (featb, el, er) -> hbuf bf16 (ELU, no residual)
    gemm_mfma<256, false><<<dim3(NBM, 2), 256, 0, stream>>>(x, Bt0, al0, ar0, featb, el, er,
                                                            nullptr, NNODES);
    agg4_kernel<0, true><<<NB4, 256, 0, stream>>>(featb, el, er, row_start, csr_src,
                                                  nullptr, b0, hbuf, NNODES);
    // ---- layer 1: hbuf bf16 -> (featb, el, er) -> hbuf bf16 (ELU, identity residual)
    gemm_mfma<256, true><<<dim3(NBM, 2), 256, 0, stream>>>(hbuf, Bt1, al1, ar1, featb, el, er,
                                                           nullptr, NNODES);
    agg4_kernel<1, true><<<NB4, 256, 0, stream>>>(featb, el, er, row_start, csr_src,
                                                  hbuf, b1, hbuf, NNODES);
    // ---- layer 2: hbuf bf16 @ [W2|res_w2]^T -> (featb[n][64], el, er, resid) -> out fp32
    gemm_mfma<128, true><<<dim3(NBM, 1), 256, 0, stream>>>(hbuf, Bt2, al2, ar2, featb, el, er,
                                                           resid, NNODES);
    agg1_kernel<<<NB4, 256, 0, stream>>>(featb, el, er, row_start, csr_src,
                                         resid, b2, out, NNODES);
}

// Round 8
// 438.792 us; speedup vs baseline: 2.2815x; 1.0186x over previous
//
#include <hip/hip_runtime.h>
#include <math.h>

#define NNODES 50000
#define NEDGES 800000
#define NSB 49       // scan blocks: ceil(50000/1024)
#define NPACK 640    // weight-pack blocks
#define NCVT 3125    // x->bf16 convert blocks: 50000*256/(256*16)

__device__ __forceinline__ float leaky(float x) { return x > 0.f ? x : 0.2f * x; }

__device__ __forceinline__ ushort f2bf(float f) {
    unsigned u = __float_as_uint(f);
    return (ushort)((u + 0x7fffu + ((u >> 16) & 1u)) >> 16);  // RNE
}
__device__ __forceinline__ float bf2f(ushort u) {
    return __uint_as_float((unsigned)u << 16);
}

typedef const __attribute__((address_space(1))) void* gptr_t;
typedef __attribute__((address_space(3))) void* lptr_t;

// ---------------- CSR build ----------------
__global__ void hist_kernel(const int* __restrict__ dst, int* __restrict__ counts) {
    int e = blockIdx.x * 256 + threadIdx.x;
    if (e < NEDGES) atomicAdd(&counts[dst[e]], 1);
}

// fused: [0,NSB) scan_partial | [NSB,NSB+NPACK) weight pack | rest: x->bf16 convert
__global__ __launch_bounds__(256) void prep_kernel(
    const int* __restrict__ counts, int* __restrict__ bsum, int Nn,
    const float* __restrict__ W0, const float* __restrict__ W1, const float* __restrict__ W2,
    const float* __restrict__ Wr, ushort* __restrict__ Bt0, ushort* __restrict__ Bt1,
    ushort* __restrict__ Bt2, const float* __restrict__ x, ushort* __restrict__ xb) {
    using ushort8v = __attribute__((ext_vector_type(8))) unsigned short;
    int t = threadIdx.x;
    if (blockIdx.x < NSB) {
        int b = blockIdx.x;
        int base = b * 1024;
        int v = 0;
#pragma unroll
        for (int i = 0; i < 4; ++i) {
            int idx = base + t + 256 * i;
            if (idx < Nn) v += counts[idx];
        }
        for (int o = 32; o; o >>= 1) v += __shfl_xor(v, o);
        __shared__ int ws[4];
        if ((t & 63) == 0) ws[t >> 6] = v;
        __syncthreads();
        if (t == 0) bsum[b] = ws[0] + ws[1] + ws[2] + ws[3];
    } else if (blockIdx.x < NSB + NPACK) {
        int idx = (blockIdx.x - NSB) * 256 + t;  // 0..163839
        if (idx < 65536) {
            int n = idx >> 8, k = idx & 255;
            Bt0[idx] = f2bf(W0[k * 256 + n]);
        } else if (idx < 131072) {
            int j = idx - 65536;
            int n = j >> 8, k = j & 255;
            Bt1[j] = f2bf(W1[k * 256 + n]);
        } else {
            int j = idx - 131072;
            int n = j >> 8, k = j & 255;
            Bt2[j] = f2bf(n < 64 ? W2[k * 64 + n] : Wr[k * 64 + (n - 64)]);
        }
    } else {
        size_t j = (size_t)(blockIdx.x - NSB - NPACK) * 4096 + t * 16;  // exact: 3125*4096 = 12.8M
        float4 a0 = *reinterpret_cast<const float4*>(x + j);
        float4 a1 = *reinterpret_cast<const float4*>(x + j + 4);
        float4 a2 = *reinterpret_cast<const float4*>(x + j + 8);
        float4 a3 = *reinterpret_cast<const float4*>(x + j + 12);
        union { ushort8v v; ushort u[8]; } p0, p1;
        p0.u[0] = f2bf(a0.x); p0.u[1] = f2bf(a0.y); p0.u[2] = f2bf(a0.z); p0.u[3] = f2bf(a0.w);
        p0.u[4] = f2bf(a1.x); p0.u[5] = f2bf(a1.y); p0.u[6] = f2bf(a1.z); p0.u[7] = f2bf(a1.w);
        p1.u[0] = f2bf(a2.x); p1.u[1] = f2bf(a2.y); p1.u[2] = f2bf(a2.z); p1.u[3] = f2bf(a2.w);
        p1.u[4] = f2bf(a3.x); p1.u[5] = f2bf(a3.y); p1.u[6] = f2bf(a3.z); p1.u[7] = f2bf(a3.w);
        *reinterpret_cast<ushort8v*>(xb + j) = p0.v;
        *reinterpret_cast<ushort8v*>(xb + j + 8) = p1.v;
    }
}

__global__ __launch_bounds__(256) void scan_final(const int* __restrict__ counts,
                                                  const int* __restrict__ bsum,
                                                  int* __restrict__ row_start, int Nn, int nB) {
    __shared__ int off_s;
    __shared__ int tsum[256];
    int b = blockIdx.x, t = threadIdx.x;
    if (t == 0) {
        int o = 0;
        for (int i = 0; i < b; ++i) o += bsum[i];
        off_s = o;
    }
    int base = b * 1024 + t * 4;
    int c0 = 0, c1 = 0, c2 = 0, c3 = 0;
    if (base + 3 < Nn) {
        int4 c = *reinterpret_cast<const int4*>(counts + base);
        c0 = c.x; c1 = c.y; c2 = c.z; c3 = c.w;
    } else {
        if (base + 0 < Nn) c0 = counts[base + 0];
        if (base + 1 < Nn) c1 = counts[base + 1];
        if (base + 2 < Nn) c2 = counts[base + 2];
        if (base + 3 < Nn) c3 = counts[base + 3];
    }
    int s0 = c0, s1 = s0 + c1, s2 = s1 + c2, s3 = s2 + c3;
    tsum[t] = s3;
    __syncthreads();
    for (int o = 1; o < 256; o <<= 1) {
        int u = (t >= o) ? tsum[t - o] : 0;
        __syncthreads();
        tsum[t] += u;
        __syncthreads();
    }
    int o = off_s + tsum[t] - s3;
    if (base + 3 < Nn) {
        *reinterpret_cast<int4*>(row_start + base) = make_int4(o, o + s0, o + s1, o + s2);
    } else {
        if (base + 0 < Nn) row_start[base + 0] = o;
        if (base + 1 < Nn) row_start[base + 1] = o + s0;
        if (base + 2 < Nn) row_start[base + 2] = o + s1;
        if (base + 3 < Nn) row_start[base + 3] = o + s2;
    }
    if (b == nB - 1 && t == 255) row_start[Nn] = off_s + tsum[255];
}

__global__ void scatter_kernel(const int* __restrict__ src, const int* __restrict__ dst,
                               const int* __restrict__ row_start, int* __restrict__ cursor,
                               int* __restrict__ csr_src) {
    int e = blockIdx.x * 256 + threadIdx.x;
    if (e < NEDGES) {
        int d = dst[e];
        int pos = row_start[d] + atomicAdd(&cursor[d], 1);
        csr_src[pos] = src[e];
    }
}

// ---- 512-thread MFMA GEMM, 128x256 per block, bf16 A via global_load_lds ----
// 8 waves: wr=wave>>2 (row 64-tile), wc=wave&3 (col 64-tile = head).
// Epilogue: featb bf16 head-interleaved + el/er (head = wc).
__global__ __launch_bounds__(512) void gemm_wide(const ushort* __restrict__ Ab,
                                                 const ushort* __restrict__ Bt,
                                                 const float* __restrict__ al,
                                                 const float* __restrict__ ar,
                                                 ushort* __restrict__ featb,
                                                 float* __restrict__ el, float* __restrict__ er,
                                                 int Nrows) {
    using bf16x8 = __attribute__((ext_vector_type(8))) short;
    using f32x4 = __attribute__((ext_vector_type(4))) float;
    __shared__ ushort As[8192];   // 128 rows x 64 k (1024 x 16B chunks)
    __shared__ ushort Bs[16384];  // 256 cols x 64 k (2048 x 16B chunks)
    const int tid = threadIdx.x;
    const int lane = tid & 63;
    const int wave = tid >> 6;
    const int wr = wave >> 2, wc = wave & 3;
    const int q = lane >> 4, li = lane & 15;
    const int r0 = blockIdx.x * 128;

    f32x4 acc[4][4];
#pragma unroll
    for (int i = 0; i < 4; ++i)
#pragma unroll
        for (int j = 0; j < 4; ++j) acc[i][j] = (f32x4){0.f, 0.f, 0.f, 0.f};

    for (int kk = 0; kk < 256; kk += 64) {
        __syncthreads();
        // A: 1024 chunks, 2 per thread
#pragma unroll
        for (int j = 0; j < 2; ++j) {
            int c = wave * 128 + j * 64 + lane;
            int mr = c & 15, kg = (c >> 4) & 7, mf = c >> 7;
            const ushort* gp = Ab + (size_t)(r0 + mf * 16 + mr) * 256 + kk + kg * 8;
            void* lp = (char*)As + (size_t)(wave * 2 + j) * 1024;
            __builtin_amdgcn_global_load_lds((gptr_t)gp, (lptr_t)lp, 16, 0, 0);
        }
        // B: 2048 chunks, 4 per thread
#pragma unroll
        for (int j = 0; j < 4; ++j) {
            int c = wave * 256 + j * 64 + lane;
            int nr = c & 15, kg = (c >> 4) & 7, nf = c >> 7;
            const ushort* gp = Bt + (size_t)(nf * 16 + nr) * 256 + kk + kg * 8;
            void* lp = (char*)Bs + (size_t)(wave * 4 + j) * 1024;
            __builtin_amdgcn_global_load_lds((gptr_t)gp, (lptr_t)lp, 16, 0, 0);
        }
        __syncthreads();
#pragma unroll
        for (int t = 0; t < 2; ++t) {
            const int kc = t * 4 + q;
            bf16x8 af[4], bfv[4];
#pragma unroll
            for (int f = 0; f < 4; ++f) {
                af[f] = *reinterpret_cast<const bf16x8*>(
                    &As[(((wr * 4 + f) * 8 + kc) * 16 + li) * 8]);
                bfv[f] = *reinterpret_cast<const bf16x8*>(
                    &Bs[(((wc * 4 + f) * 8 + kc) * 16 + li) * 8]);
            }
#pragma unroll
            for (int f = 0; f < 4; ++f)
#pragma unroll
                for (int f2 = 0; f2 < 4; ++f2)
                    acc[f][f2] =
                        __builtin_amdgcn_mfma_f32_16x16x32_bf16(af[f], bfv[f2], acc[f][f2], 0, 0, 0);
        }
    }

    // epilogue: head = wc
    float alv[4], arv[4];
#pragma unroll
    for (int f2 = 0; f2 < 4; ++f2) {
        alv[f2] = al[wc * 64 + f2 * 16 + li];
        arv[f2] = ar[wc * 64 + f2 * 16 + li];
    }
#pragma unroll
    for (int f = 0; f < 4; ++f) {
#pragma unroll
        for (int r = 0; r < 4; ++r) {
            int row = r0 + wr * 64 + f * 16 + q * 4 + r;
            bool ok = row < Nrows;
            float elp = 0.f, erp = 0.f;
#pragma unroll
            for (int f2 = 0; f2 < 4; ++f2) {
                float v = acc[f][f2][r];
                elp = fmaf(v, alv[f2], elp);
                erp = fmaf(v, arv[f2], erp);
                if (ok) featb[(size_t)row * 256 + (f2 * 16 + li) * 4 + wc] = f2bf(v);
            }
#pragma unroll
            for (int o = 1; o < 16; o <<= 1) {
                elp += __shfl_xor(elp, o);
                erp += __shfl_xor(erp, o);
            }
            if (ok && li == 0) {
                el[row * 4 + wc] = elp;
                er[row * 4 + wc] = erp;
            }
        }
    }
}

// ---- layer-2 GEMM: 256 threads, 128x128, bf16 A via DMA ----
__global__ __launch_bounds__(256) void gemm_l2(const ushort* __restrict__ Ab,
                                               const ushort* __restrict__ Bt,
                                               const float* __restrict__ al,
                                               const float* __restrict__ ar,
                                               ushort* __restrict__ featb,
                                               float* __restrict__ el, float* __restrict__ er,
                                               float* __restrict__ resid, int Nrows) {
    using bf16x8 = __attribute__((ext_vector_type(8))) short;
    using f32x4 = __attribute__((ext_vector_type(4))) float;
    __shared__ ushort As[8192];
    __shared__ ushort Bs[8192];
    const int tid = threadIdx.x;
    const int lane = tid & 63;
    const int wave = tid >> 6;
    const int wr = wave >> 1, wc = wave & 1;
    const int q = lane >> 4, li = lane & 15;
    const int r0 = blockIdx.x * 128;

    f32x4 acc[4][4];
#pragma unroll
    for (int i = 0; i < 4; ++i)
#pragma unroll
        for (int j = 0; j < 4; ++j) acc[i][j] = (f32x4){0.f, 0.f, 0.f, 0.f};

    for (int kk = 0; kk < 256; kk += 64) {
        __syncthreads();
#pragma unroll
        for (int j = 0; j < 4; ++j) {
            int c = (wave * 4 + j) * 64 + lane;
            int mr = c & 15, kg = (c >> 4) & 7, mf = c >> 7;
            const ushort* gp = Ab + (size_t)(r0 + mf * 16 + mr) * 256 + kk + kg * 8;
            void* lp = (char*)As + (size_t)(wave * 4 + j) * 1024;
            __builtin_amdgcn_global_load_lds((gptr_t)gp, (lptr_t)lp, 16, 0, 0);
        }
#pragma unroll
        for (int j = 0; j < 4; ++j) {
            int c = (wave * 4 + j) * 64 + lane;
            int nr = c & 15, kg = (c >> 4) & 7, nf = c >> 7;
            const ushort* gp = Bt + (size_t)(nf * 16 + nr) * 256 + kk + kg * 8;
            void* lp = (char*)Bs + (size_t)(wave * 4 + j) * 1024;
            __builtin_amdgcn_global_load_lds((gptr_t)gp, (lptr_t)lp, 16, 0, 0);
        }
        __syncthreads();
#pragma unroll
        for (int t = 0; t < 2; ++t) {
            const int kc = t * 4 + q;
            bf16x8 af[4], bfv[4];
#pragma unroll
            for (int f = 0; f < 4; ++f) {
                af[f] = *reinterpret_cast<const bf16x8*>(
                    &As[(((wr * 4 + f) * 8 + kc) * 16 + li) * 8]);
                bfv[f] = *reinterpret_cast<const bf16x8*>(
                    &Bs[(((wc * 4 + f) * 8 + kc) * 16 + li) * 8]);
            }
#pragma unroll
            for (int f = 0; f < 4; ++f)
#pragma unroll
                for (int f2 = 0; f2 < 4; ++f2)
                    acc[f][f2] =
                        __builtin_amdgcn_mfma_f32_16x16x32_bf16(af[f], bfv[f2], acc[f][f2], 0, 0, 0);
        }
    }

    if (wc == 0) {  // head half: featb + el/er
        float alv[4], arv[4];
#pragma unroll
        for (int f2 = 0; f2 < 4; ++f2) {
            alv[f2] = al[f2 * 16 + li];
            arv[f2] = ar[f2 * 16 + li];
        }
#pragma unroll
        for (int f = 0; f < 4; ++f) {
#pragma unroll
            for (int r = 0; r < 4; ++r) {
                int row = r0 + wr * 64 + f * 16 + q * 4 + r;
                bool ok = row < Nrows;
                float elp = 0.f, erp = 0.f;
#pragma unroll
                for (int f2 = 0; f2 < 4; ++f2) {
                    float v = acc[f][f2][r];
                    elp = fmaf(v, alv[f2], elp);
                    erp = fmaf(v, arv[f2], erp);
                    if (ok) featb[(size_t)row * 64 + f2 * 16 + li] = f2bf(v);
                }
#pragma unroll
                for (int o = 1; o < 16; o <<= 1) {
                    elp += __shfl_xor(elp, o);
                    erp += __shfl_xor(erp, o);
                }
                if (ok && li == 0) {
                    el[row] = elp;
                    er[row] = erp;
                }
            }
        }
    } else {  // residual half
#pragma unroll
        for (int f = 0; f < 4; ++f) {
#pragma unroll
            for (int r = 0; r < 4; ++r) {
                int row = r0 + wr * 64 + f * 16 + q * 4 + r;
                if (row < Nrows) {
#pragma unroll
                    for (int f2 = 0; f2 < 4; ++f2)
                        resid[(size_t)row * 64 + f2 * 16 + li] = acc[f][f2][r];
                }
            }
        }
    }
}

// ---------------- agg H=4: 2 edges/iter, 32 lanes x ushort8 (16B) each ----------------
template <int RES, bool ACT>
__global__ __launch_bounds__(256) void agg4_kernel(
    const ushort* __restrict__ featb, const float* __restrict__ el,
    const float* __restrict__ er, const int* __restrict__ row_start,
    const int* __restrict__ csr_src, const ushort* __restrict__ resbuf,
    const float* __restrict__ bias, ushort* __restrict__ out, int Nn) {
    using ushort8v = __attribute__((ext_vector_type(8))) unsigned short;
    __shared__ float wbuf[4][256];
    __shared__ int obuf[4][64];
    const int wv = threadIdx.x >> 6, lane = threadIdx.x & 63;
    const int g = lane >> 5, li = lane & 31;
    int node = blockIdx.x * 4 + wv;
    if (node >= Nn) return;

    int begin = row_start[node], end = row_start[node + 1];
    float4 ern = *(reinterpret_cast<const float4*>(er) + node);

    float denom[4] = {0.f, 0.f, 0.f, 0.f};
    float acc[2][4] = {{0.f, 0.f, 0.f, 0.f}, {0.f, 0.f, 0.f, 0.f}};

    for (int c = begin; c < end; c += 64) {
        int nE = min(64, end - c);
        float4 w = make_float4(0.f, 0.f, 0.f, 0.f);
        int s = 0;
        if (lane < nE) {
            s = csr_src[c + lane];
            float4 e4 = *(reinterpret_cast<const float4*>(el) + s);
            w.x = __expf(leaky(e4.x + ern.x));
            w.y = __expf(leaky(e4.y + ern.y));
            w.z = __expf(leaky(e4.z + ern.z));
            w.w = __expf(leaky(e4.w + ern.w));
        }
        denom[0] += w.x; denom[1] += w.y; denom[2] += w.z; denom[3] += w.w;
        obuf[wv][lane] = s * 256;
        *reinterpret_cast<float4*>(&wbuf[wv][lane * 4]) = w;
        __asm__ volatile("s_waitcnt lgkmcnt(0)" ::: "memory");

#pragma unroll 4
        for (int e2 = 0; e2 < nE; e2 += 2) {
            int e = e2 + g;
            float4 we = make_float4(0.f, 0.f, 0.f, 0.f);
            int off = 0;
            if (e < nE) {
                off = obuf[wv][e];
                we = *reinterpret_cast<const float4*>(&wbuf[wv][e * 4]);
            }
            ushort8v v = *reinterpret_cast<const ushort8v*>(featb + off + li * 8);
            acc[0][0] = fmaf(we.x, bf2f(v[0]), acc[0][0]);
            acc[0][1] = fmaf(we.y, bf2f(v[1]), acc[0][1]);
            acc[0][2] = fmaf(we.z, bf2f(v[2]), acc[0][2]);
            acc[0][3] = fmaf(we.w, bf2f(v[3]), acc[0][3]);
            acc[1][0] = fmaf(we.x, bf2f(v[4]), acc[1][0]);
            acc[1][1] = fmaf(we.y, bf2f(v[5]), acc[1][1]);
            acc[1][2] = fmaf(we.z, bf2f(v[6]), acc[1][2]);
            acc[1][3] = fmaf(we.w, bf2f(v[7]), acc[1][3]);
        }
        __asm__ volatile("" ::: "memory");
    }

#pragma unroll
    for (int j = 0; j < 2; ++j)
#pragma unroll
        for (int h = 0; h < 4; ++h) acc[j][h] += __shfl_xor(acc[j][h], 32);
#pragma unroll
    for (int h = 0; h < 4; ++h)
        for (int o = 32; o; o >>= 1) denom[h] += __shfl_xor(denom[h], o);

    bool has = end > begin;
#pragma unroll
    for (int hh = 0; hh < 2; ++hh) {
        int h = g * 2 + hh;
        float d0 = denom[h];
        float o0 = has ? acc[0][h] / d0 : 0.f;
        float o1 = has ? acc[1][h] / d0 : 0.f;
        int dbase = h * 64 + li * 2;
        if constexpr (RES == 1) {
            unsigned rv = *reinterpret_cast<const unsigned*>(resbuf + (size_t)node * 256 + dbase);
            o0 += bf2f((ushort)(rv & 0xffffu));
            o1 += bf2f((ushort)(rv >> 16));
        }
        float2 bv = *reinterpret_cast<const float2*>(bias + dbase);
        o0 += bv.x; o1 += bv.y;
        if constexpr (ACT) {
            o0 = o0 > 0.f ? o0 : __expf(o0) - 1.f;
            o1 = o1 > 0.f ? o1 : __expf(o1) - 1.f;
        }
        unsigned pk = (unsigned)f2bf(o0) | ((unsigned)f2bf(o1) << 16);
        *reinterpret_cast<unsigned*>(out + (size_t)node * 256 + dbase) = pk;
    }
}

// ---------------- agg H=1 (layer 2) ----------------
__global__ __launch_bounds__(256) void agg1_kernel(
    const ushort* __restrict__ featb, const float* __restrict__ el,
    const float* __restrict__ er, const int* __restrict__ row_start,
    const int* __restrict__ csr_src, const float* __restrict__ resbuf,
    const float* __restrict__ bias, float* __restrict__ out, int Nn) {
    __shared__ float wbuf[4][64];
    __shared__ int obuf[4][64];
    const int wv = threadIdx.x >> 6, lane = threadIdx.x & 63;
    const int g = lane >> 4, li = lane & 15;
    int node = blockIdx.x * 4 + wv;
    if (node >= Nn) return;

    int begin = row_start[node], end = row_start[node + 1];
    float ern = er[node];
    float denom = 0.f;
    float acc[4] = {0.f, 0.f, 0.f, 0.f};

    for (int c = begin; c < end; c += 64) {
        int nE = min(64, end - c);
        float w = 0.f;
        int s = 0;
        if (lane < nE) {
            s = csr_src[c + lane];
            w = __expf(leaky(el[s] + ern));
        }
        denom += w;
        obuf[wv][lane] = s * 64;
        wbuf[wv][lane] = w;
        __asm__ volatile("s_waitcnt lgkmcnt(0)" ::: "memory");

#pragma unroll 2
        for (int e4i = 0; e4i < nE; e4i += 4) {
            int e = e4i + g;
            float we = 0.f;
            int off = 0;
            if (e < nE) {
                off = obuf[wv][e];
                we = wbuf[wv][e];
            }
            ushort4 v = *reinterpret_cast<const ushort4*>(featb + off + li * 4);
            acc[0] = fmaf(we, bf2f(v.x), acc[0]);
            acc[1] = fmaf(we, bf2f(v.y), acc[1]);
            acc[2] = fmaf(we, bf2f(v.z), acc[2]);
            acc[3] = fmaf(we, bf2f(v.w), acc[3]);
        }
        __asm__ volatile("" ::: "memory");
    }

#pragma unroll
    for (int j = 0; j < 4; ++j) {
        acc[j] += __shfl_xor(acc[j], 16);
        acc[j] += __shfl_xor(acc[j], 32);
    }
    for (int o = 32; o; o >>= 1) denom += __shfl_xor(denom, o);

    if (g == 0) {
        bool has = end > begin;
        float4 rv = *reinterpret_cast<const float4*>(resbuf + (size_t)node * 64 + li * 4);
        float4 bv = *reinterpret_cast<const float4*>(bias + li * 4);
        float4 o4;
        o4.x = (has ? acc[0] / denom : 0.f) + rv.x + bv.x;
        o4.y = (has ? acc[1] / denom : 0.f) + rv.y + bv.y;
        o4.z = (has ? acc[2] / denom : 0.f) + rv.z + bv.z;
        o4.w = (has ? acc[3] / denom : 0.f) + rv.w + bv.w;
        *reinterpret_cast<float4*>(out + (size_t)node * 64 + li * 4) = o4;
    }
}

// ---------------- launch ----------------
extern "C" void kernel_launch(void* const* d_in, const int* in_sizes, int n_in, void* d_out,
                              int out_size, void* d_ws, size_t ws_size, hipStream_t stream) {
    const float* x   = (const float*)d_in[0];
    const int* src   = (const int*)d_in[1];
    const int* dst   = (const int*)d_in[2];
    const float* W0  = (const float*)d_in[3];
    const float* al0 = (const float*)d_in[4];
    const float* ar0 = (const float*)d_in[5];
    const float* b0  = (const float*)d_in[6];
    const float* W1  = (const float*)d_in[7];
    const float* al1 = (const float*)d_in[8];
    const float* ar1 = (const float*)d_in[9];
    const float* b1  = (const float*)d_in[10];
    const float* W2  = (const float*)d_in[11];
    const float* al2 = (const float*)d_in[12];
    const float* ar2 = (const float*)d_in[13];
    const float* b2  = (const float*)d_in[14];
    const float* Wr2 = (const float*)d_in[15];
    float* out = (float*)d_out;

    char* w = (char*)d_ws;
    size_t off = 0;
    auto alloc = [&](size_t bytes) -> char* {
        char* p = w + off;
        off += (bytes + 255) & ~(size_t)255;
        return p;
    };
    ushort* xb      = (ushort*)alloc((size_t)NNODES * 256 * 2);  // bf16 x
    ushort* hbuf    = (ushort*)alloc((size_t)NNODES * 256 * 2);  // bf16 h0/h1
    ushort* featb   = (ushort*)alloc((size_t)NNODES * 256 * 2);  // bf16 messages
    float* resid    = (float*)alloc((size_t)NNODES * 64 * 4);
    float* el       = (float*)alloc((size_t)NNODES * 4 * 4);
    float* er       = (float*)alloc((size_t)NNODES * 4 * 4);
    ushort* Bt0     = (ushort*)alloc(65536 * 2);
    ushort* Bt1     = (ushort*)alloc(65536 * 2);
    ushort* Bt2     = (ushort*)alloc(32768 * 2);
    int* counts     = (int*)alloc((size_t)NNODES * 4 * 2);
    int* cursor     = counts + NNODES;
    int* row_start  = (int*)alloc((size_t)(NNODES + 1) * 4);
    int* bsum       = (int*)alloc(64 * 4);
    int* csr_src    = (int*)alloc((size_t)NEDGES * 4);

    hipMemsetAsync(counts, 0, (size_t)NNODES * 4 * 2, stream);

    const int EB = (NEDGES + 255) / 256;
    const int NB4 = (NNODES + 3) / 4;
    const int NBM = (NNODES + 127) / 128;

    hist_kernel<<<EB, 256, 0, stream>>>(dst, counts);
    prep_kernel<<<NSB + NPACK + NCVT, 256, 0, stream>>>(counts, bsum, NNODES, W0, W1, W2, Wr2,
                                                        Bt0, Bt1, Bt2, x, xb);
    scan_final<<<NSB, 256, 0, stream>>>(counts, bsum, row_start, NNODES, NSB);
    scatter_kernel<<<EB, 256, 0, stream>>>(src, dst, row_start, cursor, csr_src);

    // ---- layer 0: xb -> (featb, el, er) -> hbuf bf16 (ELU, no residual)
    gemm_wide<<<NBM, 512, 0, stream>>>(xb, Bt0, al0, ar0, featb, el, er, NNODES);
    agg4_kernel<0, true><<<NB4, 256, 0, stream>>>(featb, el, er, row_start, csr_src,
                                                  nullptr, b0, hbuf, NNODES);
    // ---- layer 1: hbuf -> (featb, el, er) -> hbuf (ELU, identity residual)
    gemm_wide<<<NBM, 512, 0, stream>>>(hbuf, Bt1, al1, ar1, featb, el, er, NNODES);
    agg4_kernel<1, true><<<NB4, 256, 0, stream>>>(featb, el, er, row_start, csr_src,
                                                  hbuf, b1, hbuf, NNODES);
    // ---- layer 2: hbuf @ [W2|res_w2]^T -> (featb[n][64], el, er, resid) -> out fp32
    gemm_l2<<<NBM, 256, 0, stream>>>(hbuf, Bt2, al2, ar2, featb, el, er, resid, NNODES);
    agg1_kernel<<<NB4, 256, 0, stream>>>(featb, el, er, row_start, csr_src,
                                         resid, b2, out, NNODES);
}

// Round 9
// 419.228 us; speedup vs baseline: 2.3879x; 1.0467x over previous
//
#include <hip/hip_runtime.h>
#include <math.h>

#define NNODES 50000
#define NEDGES 800000
#define NSB 49       // scan blocks: ceil(50000/1024)
#define NPACK 640    // weight-pack blocks
#define NCVT 3125    // x->bf16 convert blocks: 50000*256/(256*16)
#define EBH 3125     // hist blocks: 800000/256
#define NBM 391      // gemm row-tile blocks: ceil(50000/128)
#define SCB 1563     // scatter blocks @512: ceil(800000/512)

__device__ __forceinline__ float leaky(float x) { return x > 0.f ? x : 0.2f * x; }

__device__ __forceinline__ ushort f2bf(float f) {
    unsigned u = __float_as_uint(f);
    return (ushort)((u + 0x7fffu + ((u >> 16) & 1u)) >> 16);  // RNE
}
__device__ __forceinline__ float bf2f(ushort u) {
    return __uint_as_float((unsigned)u << 16);
}

typedef const __attribute__((address_space(1))) void* gptr_t;
typedef __attribute__((address_space(3))) void* lptr_t;

// ---- front: hist | weight pack | x->bf16 convert (independent work, one dispatch) ----
__global__ __launch_bounds__(256) void front_kernel(
    const int* __restrict__ dst, int* __restrict__ counts,
    const float* __restrict__ W0, const float* __restrict__ W1, const float* __restrict__ W2,
    const float* __restrict__ Wr, ushort* __restrict__ Bt0, ushort* __restrict__ Bt1,
    ushort* __restrict__ Bt2, const float* __restrict__ x, ushort* __restrict__ xb) {
    using ushort8v = __attribute__((ext_vector_type(8))) unsigned short;
    int t = threadIdx.x;
    if (blockIdx.x < EBH) {
        int e = blockIdx.x * 256 + t;
        if (e < NEDGES) atomicAdd(&counts[dst[e]], 1);
    } else if (blockIdx.x < EBH + NPACK) {
        int idx = (blockIdx.x - EBH) * 256 + t;  // 0..163839
        if (idx < 65536) {
            int n = idx >> 8, k = idx & 255;
            Bt0[idx] = f2bf(W0[k * 256 + n]);
        } else if (idx < 131072) {
            int j = idx - 65536;
            int n = j >> 8, k = j & 255;
            Bt1[j] = f2bf(W1[k * 256 + n]);
        } else {
            int j = idx - 131072;
            int n = j >> 8, k = j & 255;
            Bt2[j] = f2bf(n < 64 ? W2[k * 64 + n] : Wr[k * 64 + (n - 64)]);
        }
    } else {
        size_t j = (size_t)(blockIdx.x - EBH - NPACK) * 4096 + t * 16;  // 3125*4096 = 12.8M exact
        float4 a0 = *reinterpret_cast<const float4*>(x + j);
        float4 a1 = *reinterpret_cast<const float4*>(x + j + 4);
        float4 a2 = *reinterpret_cast<const float4*>(x + j + 8);
        float4 a3 = *reinterpret_cast<const float4*>(x + j + 12);
        union { ushort8v v; ushort u[8]; } p0, p1;
        p0.u[0] = f2bf(a0.x); p0.u[1] = f2bf(a0.y); p0.u[2] = f2bf(a0.z); p0.u[3] = f2bf(a0.w);
        p0.u[4] = f2bf(a1.x); p0.u[5] = f2bf(a1.y); p0.u[6] = f2bf(a1.z); p0.u[7] = f2bf(a1.w);
        p1.u[0] = f2bf(a2.x); p1.u[1] = f2bf(a2.y); p1.u[2] = f2bf(a2.z); p1.u[3] = f2bf(a2.w);
        p1.u[4] = f2bf(a3.x); p1.u[5] = f2bf(a3.y); p1.u[6] = f2bf(a3.z); p1.u[7] = f2bf(a3.w);
        *reinterpret_cast<ushort8v*>(xb + j) = p0.v;
        *reinterpret_cast<ushort8v*>(xb + j + 8) = p1.v;
    }
}

__global__ __launch_bounds__(256) void scan_partial(const int* __restrict__ counts,
                                                    int* __restrict__ bsum, int Nn) {
    int b = blockIdx.x, t = threadIdx.x;
    int base = b * 1024;
    int v = 0;
#pragma unroll
    for (int i = 0; i < 4; ++i) {
        int idx = base + t + 256 * i;
        if (idx < Nn) v += counts[idx];
    }
    for (int o = 32; o; o >>= 1) v += __shfl_xor(v, o);
    __shared__ int ws[4];
    if ((t & 63) == 0) ws[t >> 6] = v;
    __syncthreads();
    if (t == 0) bsum[b] = ws[0] + ws[1] + ws[2] + ws[3];
}

__global__ __launch_bounds__(256) void scan_final(const int* __restrict__ counts,
                                                  const int* __restrict__ bsum,
                                                  int* __restrict__ row_start, int Nn, int nB) {
    __shared__ int off_s;
    __shared__ int tsum[256];
    int b = blockIdx.x, t = threadIdx.x;
    if (t == 0) {
        int o = 0;
        for (int i = 0; i < b; ++i) o += bsum[i];
        off_s = o;
    }
    int base = b * 1024 + t * 4;
    int c0 = 0, c1 = 0, c2 = 0, c3 = 0;
    if (base + 3 < Nn) {
        int4 c = *reinterpret_cast<const int4*>(counts + base);
        c0 = c.x; c1 = c.y; c2 = c.z; c3 = c.w;
    } else {
        if (base + 0 < Nn) c0 = counts[base + 0];
        if (base + 1 < Nn) c1 = counts[base + 1];
        if (base + 2 < Nn) c2 = counts[base + 2];
        if (base + 3 < Nn) c3 = counts[base + 3];
    }
    int s0 = c0, s1 = s0 + c1, s2 = s1 + c2, s3 = s2 + c3;
    tsum[t] = s3;
    __syncthreads();
    for (int o = 1; o < 256; o <<= 1) {
        int u = (t >= o) ? tsum[t - o] : 0;
        __syncthreads();
        tsum[t] += u;
        __syncthreads();
    }
    int o = off_s + tsum[t] - s3;
    if (base + 3 < Nn) {
        *reinterpret_cast<int4*>(row_start + base) = make_int4(o, o + s0, o + s1, o + s2);
    } else {
        if (base + 0 < Nn) row_start[base + 0] = o;
        if (base + 1 < Nn) row_start[base + 1] = o + s0;
        if (base + 2 < Nn) row_start[base + 2] = o + s1;
        if (base + 3 < Nn) row_start[base + 3] = o + s2;
    }
    if (b == nB - 1 && t == 255) row_start[Nn] = off_s + tsum[255];
}

// ---- 512-thread MFMA GEMM, 128x256 per block; optional fused scatter blocks ----
// SCAT=true: blocks [0,NBM) do GEMM, [NBM, NBM+SCB) do CSR scatter (overlapped).
template <bool SCAT>
__global__ __launch_bounds__(512) void gemm_wide(const ushort* __restrict__ Ab,
                                                 const ushort* __restrict__ Bt,
                                                 const float* __restrict__ al,
                                                 const float* __restrict__ ar,
                                                 ushort* __restrict__ featb,
                                                 float* __restrict__ el, float* __restrict__ er,
                                                 int Nrows,
                                                 const int* __restrict__ srcv,
                                                 const int* __restrict__ dstv,
                                                 const int* __restrict__ row_start,
                                                 int* __restrict__ cursor,
                                                 int* __restrict__ csr_src) {
    using bf16x8 = __attribute__((ext_vector_type(8))) short;
    using f32x4 = __attribute__((ext_vector_type(4))) float;
    __shared__ ushort As[8192];   // 128 rows x 64 k
    __shared__ ushort Bs[16384];  // 256 cols x 64 k
    if constexpr (SCAT) {
        if (blockIdx.x >= NBM) {
            int e = (blockIdx.x - NBM) * 512 + threadIdx.x;
            if (e < NEDGES) {
                int d = dstv[e];
                int pos = row_start[d] + atomicAdd(&cursor[d], 1);
                csr_src[pos] = srcv[e];
            }
            return;
        }
    }
    const int tid = threadIdx.x;
    const int lane = tid & 63;
    const int wave = tid >> 6;
    const int wr = wave >> 2, wc = wave & 3;
    const int q = lane >> 4, li = lane & 15;
    const int r0 = blockIdx.x * 128;

    f32x4 acc[4][4];
#pragma unroll
    for (int i = 0; i < 4; ++i)
#pragma unroll
        for (int j = 0; j < 4; ++j) acc[i][j] = (f32x4){0.f, 0.f, 0.f, 0.f};

    for (int kk = 0; kk < 256; kk += 64) {
        __syncthreads();
#pragma unroll
        for (int j = 0; j < 2; ++j) {
            int c = wave * 128 + j * 64 + lane;
            int mr = c & 15, kg = (c >> 4) & 7, mf = c >> 7;
            const ushort* gp = Ab + (size_t)(r0 + mf * 16 + mr) * 256 + kk + kg * 8;
            void* lp = (char*)As + (size_t)(wave * 2 + j) * 1024;
            __builtin_amdgcn_global_load_lds((gptr_t)gp, (lptr_t)lp, 16, 0, 0);
        }
#pragma unroll
        for (int j = 0; j < 4; ++j) {
            int c = wave * 256 + j * 64 + lane;
            int nr = c & 15, kg = (c >> 4) & 7, nf = c >> 7;
            const ushort* gp = Bt + (size_t)(nf * 16 + nr) * 256 + kk + kg * 8;
            void* lp = (char*)Bs + (size_t)(wave * 4 + j) * 1024;
            __builtin_amdgcn_global_load_lds((gptr_t)gp, (lptr_t)lp, 16, 0, 0);
        }
        __syncthreads();
#pragma unroll
        for (int t = 0; t < 2; ++t) {
            const int kc = t * 4 + q;
            bf16x8 af[4], bfv[4];
#pragma unroll
            for (int f = 0; f < 4; ++f) {
                af[f] = *reinterpret_cast<const bf16x8*>(
                    &As[(((wr * 4 + f) * 8 + kc) * 16 + li) * 8]);
                bfv[f] = *reinterpret_cast<const bf16x8*>(
                    &Bs[(((wc * 4 + f) * 8 + kc) * 16 + li) * 8]);
            }
#pragma unroll
            for (int f = 0; f < 4; ++f)
#pragma unroll
                for (int f2 = 0; f2 < 4; ++f2)
                    acc[f][f2] =
                        __builtin_amdgcn_mfma_f32_16x16x32_bf16(af[f], bfv[f2], acc[f][f2], 0, 0, 0);
        }
    }

    float alv[4], arv[4];
#pragma unroll
    for (int f2 = 0; f2 < 4; ++f2) {
        alv[f2] = al[wc * 64 + f2 * 16 + li];
        arv[f2] = ar[wc * 64 + f2 * 16 + li];
    }
#pragma unroll
    for (int f = 0; f < 4; ++f) {
#pragma unroll
        for (int r = 0; r < 4; ++r) {
            int row = r0 + wr * 64 + f * 16 + q * 4 + r;
            bool ok = row < Nrows;
            float elp = 0.f, erp = 0.f;
#pragma unroll
            for (int f2 = 0; f2 < 4; ++f2) {
                float v = acc[f][f2][r];
                elp = fmaf(v, alv[f2], elp);
                erp = fmaf(v, arv[f2], erp);
                if (ok) featb[(size_t)row * 256 + (f2 * 16 + li) * 4 + wc] = f2bf(v);
            }
#pragma unroll
            for (int o = 1; o < 16; o <<= 1) {
                elp += __shfl_xor(elp, o);
                erp += __shfl_xor(erp, o);
            }
            if (ok && li == 0) {
                el[row * 4 + wc] = elp;
                er[row * 4 + wc] = erp;
            }
        }
    }
}

// ---- layer-2 GEMM: 256 threads, 128x128 ----
__global__ __launch_bounds__(256) void gemm_l2(const ushort* __restrict__ Ab,
                                               const ushort* __restrict__ Bt,
                                               const float* __restrict__ al,
                                               const float* __restrict__ ar,
                                               ushort* __restrict__ featb,
                                               float* __restrict__ el, float* __restrict__ er,
                                               float* __restrict__ resid, int Nrows) {
    using bf16x8 = __attribute__((ext_vector_type(8))) short;
    using f32x4 = __attribute__((ext_vector_type(4))) float;
    __shared__ ushort As[8192];
    __shared__ ushort Bs[8192];
    const int tid = threadIdx.x;
    const int lane = tid & 63;
    const int wave = tid >> 6;
    const int wr = wave >> 1, wc = wave & 1;
    const int q = lane >> 4, li = lane & 15;
    const int r0 = blockIdx.x * 128;

    f32x4 acc[4][4];
#pragma unroll
    for (int i = 0; i < 4; ++i)
#pragma unroll
        for (int j = 0; j < 4; ++j) acc[i][j] = (f32x4){0.f, 0.f, 0.f, 0.f};

    for (int kk = 0; kk < 256; kk += 64) {
        __syncthreads();
#pragma unroll
        for (int j = 0; j < 4; ++j) {
            int c = (wave * 4 + j) * 64 + lane;
            int mr = c & 15, kg = (c >> 4) & 7, mf = c >> 7;
            const ushort* gp = Ab + (size_t)(r0 + mf * 16 + mr) * 256 + kk + kg * 8;
            void* lp = (char*)As + (size_t)(wave * 4 + j) * 1024;
            __builtin_amdgcn_global_load_lds((gptr_t)gp, (lptr_t)lp, 16, 0, 0);
        }
#pragma unroll
        for (int j = 0; j < 4; ++j) {
            int c = (wave * 4 + j) * 64 + lane;
            int nr = c & 15, kg = (c >> 4) & 7, nf = c >> 7;
            const ushort* gp = Bt + (size_t)(nf * 16 + nr) * 256 + kk + kg * 8;
            void* lp = (char*)Bs + (size_t)(wave * 4 + j) * 1024;
            __builtin_amdgcn_global_load_lds((gptr_t)gp, (lptr_t)lp, 16, 0, 0);
        }
        __syncthreads();
#pragma unroll
        for (int t = 0; t < 2; ++t) {
            const int kc = t * 4 + q;
            bf16x8 af[4], bfv[4];
#pragma unroll
            for (int f = 0; f < 4; ++f) {
                af[f] = *reinterpret_cast<const bf16x8*>(
                    &As[(((wr * 4 + f) * 8 + kc) * 16 + li) * 8]);
                bfv[f] = *reinterpret_cast<const bf16x8*>(
                    &Bs[(((wc * 4 + f) * 8 + kc) * 16 + li) * 8]);
            }
#pragma unroll
            for (int f = 0; f < 4; ++f)
#pragma unroll
                for (int f2 = 0; f2 < 4; ++f2)
                    acc[f][f2] =
                        __builtin_amdgcn_mfma_f32_16x16x32_bf16(af[f], bfv[f2], acc[f][f2], 0, 0, 0);
        }
    }

    if (wc == 0) {
        float alv[4], arv[4];
#pragma unroll
        for (int f2 = 0; f2 < 4; ++f2) {
            alv[f2] = al[f2 * 16 + li];
            arv[f2] = ar[f2 * 16 + li];
        }
#pragma unroll
        for (int f = 0; f < 4; ++f) {
#pragma unroll
            for (int r = 0; r < 4; ++r) {
                int row = r0 + wr * 64 + f * 16 + q * 4 + r;
                bool ok = row < Nrows;
                float elp = 0.f, erp = 0.f;
#pragma unroll
                for (int f2 = 0; f2 < 4; ++f2) {
                    float v = acc[f][f2][r];
                    elp = fmaf(v, alv[f2], elp);
                    erp = fmaf(v, arv[f2], erp);
                    if (ok) featb[(size_t)row * 64 + f2 * 16 + li] = f2bf(v);
                }
#pragma unroll
                for (int o = 1; o < 16; o <<= 1) {
                    elp += __shfl_xor(elp, o);
                    erp += __shfl_xor(erp, o);
                }
                if (ok && li == 0) {
                    el[row] = elp;
                    er[row] = erp;
                }
            }
        }
    } else {
#pragma unroll
        for (int f = 0; f < 4; ++f) {
#pragma unroll
            for (int r = 0; r < 4; ++r) {
                int row = r0 + wr * 64 + f * 16 + q * 4 + r;
                if (row < Nrows) {
#pragma unroll
                    for (int f2 = 0; f2 < 4; ++f2)
                        resid[(size_t)row * 64 + f2 * 16 + li] = acc[f][f2][r];
                }
            }
        }
    }
}

// ---------------- agg H=4: 2 edges/iter, 32 lanes x ushort8 (16B) each ----------------
template <int RES, bool ACT>
__global__ __launch_bounds__(256) void agg4_kernel(
    const ushort* __restrict__ featb, const float* __restrict__ el,
    const float* __restrict__ er, const int* __restrict__ row_start,
    const int* __restrict__ csr_src, const ushort* __restrict__ resbuf,
    const float* __restrict__ bias, ushort* __restrict__ out, int Nn) {
    using ushort8v = __attribute__((ext_vector_type(8))) unsigned short;
    __shared__ float wbuf[4][256];
    __shared__ int obuf[4][64];
    const int wv = threadIdx.x >> 6, lane = threadIdx.x & 63;
    const int g = lane >> 5, li = lane & 31;
    int node = blockIdx.x * 4 + wv;
    if (node >= Nn) return;

    int begin = row_start[node], end = row_start[node + 1];
    float4 ern = *(reinterpret_cast<const float4*>(er) + node);

    float denom[4] = {0.f, 0.f, 0.f, 0.f};
    float acc[2][4] = {{0.f, 0.f, 0.f, 0.f}, {0.f, 0.f, 0.f, 0.f}};

    for (int c = begin; c < end; c += 64) {
        int nE = min(64, end - c);
        float4 w = make_float4(0.f, 0.f, 0.f, 0.f);
        int s = 0;
        if (lane < nE) {
            s = csr_src[c + lane];
            float4 e4 = *(reinterpret_cast<const float4*>(el) + s);
            w.x = __expf(leaky(e4.x + ern.x));
            w.y = __expf(leaky(e4.y + ern.y));
            w.z = __expf(leaky(e4.z + ern.z));
            w.w = __expf(leaky(e4.w + ern.w));
        }
        denom[0] += w.x; denom[1] += w.y; denom[2] += w.z; denom[3] += w.w;
        obuf[wv][lane] = s * 256;
        *reinterpret_cast<float4*>(&wbuf[wv][lane * 4]) = w;
        __asm__ volatile("s_waitcnt lgkmcnt(0)" ::: "memory");

#pragma unroll 4
        for (int e2 = 0; e2 < nE; e2 += 2) {
            int e = e2 + g;
            float4 we = make_float4(0.f, 0.f, 0.f, 0.f);
            int off = 0;
            if (e < nE) {
                off = obuf[wv][e];
                we = *reinterpret_cast<const float4*>(&wbuf[wv][e * 4]);
            }
            ushort8v v = *reinterpret_cast<const ushort8v*>(featb + off + li * 8);
            acc[0][0] = fmaf(we.x, bf2f(v[0]), acc[0][0]);
            acc[0][1] = fmaf(we.y, bf2f(v[1]), acc[0][1]);
            acc[0][2] = fmaf(we.z, bf2f(v[2]), acc[0][2]);
            acc[0][3] = fmaf(we.w, bf2f(v[3]), acc[0][3]);
            acc[1][0] = fmaf(we.x, bf2f(v[4]), acc[1][0]);
            acc[1][1] = fmaf(we.y, bf2f(v[5]), acc[1][1]);
            acc[1][2] = fmaf(we.z, bf2f(v[6]), acc[1][2]);
            acc[1][3] = fmaf(we.w, bf2f(v[7]), acc[1][3]);
        }
        __asm__ volatile("" ::: "memory");
    }

#pragma unroll
    for (int j = 0; j < 2; ++j)
#pragma unroll
        for (int h = 0; h < 4; ++h) acc[j][h] += __shfl_xor(acc[j][h], 32);
#pragma unroll
    for (int h = 0; h < 4; ++h)
        for (int o = 32; o; o >>= 1) denom[h] += __shfl_xor(denom[h], o);

    bool has = end > begin;
#pragma unroll
    for (int hh = 0; hh < 2; ++hh) {
        int h = g * 2 + hh;
        float d0 = denom[h];
        float o0 = has ? acc[0][h] / d0 : 0.f;
        float o1 = has ? acc[1][h] / d0 : 0.f;
        int dbase = h * 64 + li * 2;
        if constexpr (RES == 1) {
            unsigned rv = *reinterpret_cast<const unsigned*>(resbuf + (size_t)node * 256 + dbase);
            o0 += bf2f((ushort)(rv & 0xffffu));
            o1 += bf2f((ushort)(rv >> 16));
        }
        float2 bv = *reinterpret_cast<const float2*>(bias + dbase);
        o0 += bv.x; o1 += bv.y;
        if constexpr (ACT) {
            o0 = o0 > 0.f ? o0 : __expf(o0) - 1.f;
            o1 = o1 > 0.f ? o1 : __expf(o1) - 1.f;
        }
        unsigned pk = (unsigned)f2bf(o0) | ((unsigned)f2bf(o1) << 16);
        *reinterpret_cast<unsigned*>(out + (size_t)node * 256 + dbase) = pk;
    }
}

// ---------------- agg H=1 (layer 2) ----------------
__global__ __launch_bounds__(256) void agg1_kernel(
    const ushort* __restrict__ featb, const float* __restrict__ el,
    const float* __restrict__ er, const int* __restrict__ row_start,
    const int* __restrict__ csr_src, const float* __restrict__ resbuf,
    const float* __restrict__ bias, float* __restrict__ out, int Nn) {
    __shared__ float wbuf[4][64];
    __shared__ int obuf[4][64];
    const int wv = threadIdx.x >> 6, lane = threadIdx.x & 63;
    const int g = lane >> 4, li = lane & 15;
    int node = blockIdx.x * 4 + wv;
    if (node >= Nn) return;

    int begin = row_start[node], end = row_start[node + 1];
    float ern = er[node];
    float denom = 0.f;
    float acc[4] = {0.f, 0.f, 0.f, 0.f};

    for (int c = begin; c < end; c += 64) {
        int nE = min(64, end - c);
        float w = 0.f;
        int s = 0;
        if (lane < nE) {
            s = csr_src[c + lane];
            w = __expf(leaky(el[s] + ern));
        }
        denom += w;
        obuf[wv][lane] = s * 64;
        wbuf[wv][lane] = w;
        __asm__ volatile("s_waitcnt lgkmcnt(0)" ::: "memory");

#pragma unroll 2
        for (int e4i = 0; e4i < nE; e4i += 4) {
            int e = e4i + g;
            float we = 0.f;
            int off = 0;
            if (e < nE) {
                off = obuf[wv][e];
                we = wbuf[wv][e];
            }
            ushort4 v = *reinterpret_cast<const ushort4*>(featb + off + li * 4);
            acc[0] = fmaf(we, bf2f(v.x), acc[0]);
            acc[1] = fmaf(we, bf2f(v.y), acc[1]);
            acc[2] = fmaf(we, bf2f(v.z), acc[2]);
            acc[3] = fmaf(we, bf2f(v.w), acc[3]);
        }
        __asm__ volatile("" ::: "memory");
    }

#pragma unroll
    for (int j = 0; j < 4; ++j) {
        acc[j] += __shfl_xor(acc[j], 16);
        acc[j] += __shfl_xor(acc[j], 32);
    }
    for (int o = 32; o; o >>= 1) denom += __shfl_xor(denom, o);

    if (g == 0) {
        bool has = end > begin;
        float4 rv = *reinterpret_cast<const float4*>(resbuf + (size_t)node * 64 + li * 4);
        float4 bv = *reinterpret_cast<const float4*>(bias + li * 4);
        float4 o4;
        o4.x = (has ? acc[0] / denom : 0.f) + rv.x + bv.x;
        o4.y = (has ? acc[1] / denom : 0.f) + rv.y + bv.y;
        o4.z = (has ? acc[2] / denom : 0.f) + rv.z + bv.z;
        o4.w = (has ? acc[3] / denom : 0.f) + rv.w + bv.w;
        *reinterpret_cast<float4*>(out + (size_t)node * 64 + li * 4) = o4;
    }
}

// ---------------- launch ----------------
extern "C" void kernel_launch(void* const* d_in, const int* in_sizes, int n_in, void* d_out,
                              int out_size, void* d_ws, size_t ws_size, hipStream_t stream) {
    const float* x   = (const float*)d_in[0];
    const int* src   = (const int*)d_in[1];
    const int* dst   = (const int*)d_in[2];
    const float* W0  = (const float*)d_in[3];
    const float* al0 = (const float*)d_in[4];
    const float* ar0 = (const float*)d_in[5];
    const float* b0  = (const float*)d_in[6];
    const float* W1  = (const float*)d_in[7];
    const float* al1 = (const float*)d_in[8];
    const float* ar1 = (const float*)d_in[9];
    const float* b1  = (const float*)d_in[10];
    const float* W2  = (const float*)d_in[11];
    const float* al2 = (const float*)d_in[12];
    const float* ar2 = (const float*)d_in[13];
    const float* b2  = (const float*)d_in[14];
    const float* Wr2 = (const float*)d_in[15];
    float* out = (float*)d_out;

    char* w = (char*)d_ws;
    size_t off = 0;
    auto alloc = [&](size_t bytes) -> char* {
        char* p = w + off;
        off += (bytes + 255) & ~(size_t)255;
        return p;
    };
    ushort* xb      = (ushort*)alloc((size_t)NNODES * 256 * 2);
    ushort* hbuf    = (ushort*)alloc((size_t)NNODES * 256 * 2);
    ushort* featb   = (ushort*)alloc((size_t)NNODES * 256 * 2);
    float* resid    = (float*)alloc((size_t)NNODES * 64 * 4);
    float* el       = (float*)alloc((size_t)NNODES * 4 * 4);
    float* er       = (float*)alloc((size_t)NNODES * 4 * 4);
    ushort* Bt0     = (ushort*)alloc(65536 * 2);
    ushort* Bt1     = (ushort*)alloc(65536 * 2);
    ushort* Bt2     = (ushort*)alloc(32768 * 2);
    int* counts     = (int*)alloc((size_t)NNODES * 4 * 2);
    int* cursor     = counts + NNODES;
    int* row_start  = (int*)alloc((size_t)(NNODES + 1) * 4);
    int* bsum       = (int*)alloc(64 * 4);
    int* csr_src    = (int*)alloc((size_t)NEDGES * 4);

    hipMemsetAsync(counts, 0, (size_t)NNODES * 4 * 2, stream);

    const int NB4 = (NNODES + 3) / 4;

    // front: hist + pack + convert (overlapped independent work)
    front_kernel<<<EBH + NPACK + NCVT, 256, 0, stream>>>(dst, counts, W0, W1, W2, Wr2,
                                                         Bt0, Bt1, Bt2, x, xb);
    scan_partial<<<NSB, 256, 0, stream>>>(counts, bsum, NNODES);
    scan_final<<<NSB, 256, 0, stream>>>(counts, bsum, row_start, NNODES, NSB);

    // layer 0 GEMM + scatter fused (scatter hides under GEMM staging)
    gemm_wide<true><<<NBM + SCB, 512, 0, stream>>>(xb, Bt0, al0, ar0, featb, el, er, NNODES,
                                                   src, dst, row_start, cursor, csr_src);
    agg4_kernel<0, true><<<NB4, 256, 0, stream>>>(featb, el, er, row_start, csr_src,
                                                  nullptr, b0, hbuf, NNODES);
    // layer 1
    gemm_wide<false><<<NBM, 512, 0, stream>>>(hbuf, Bt1, al1, ar1, featb, el, er, NNODES,
                                              nullptr, nullptr, nullptr, nullptr, nullptr);
    agg4_kernel<1, true><<<NB4, 256, 0, stream>>>(featb, el, er, row_start, csr_src,
                                                  hbuf, b1, hbuf, NNODES);
    // layer 2
    gemm_l2<<<NBM, 256, 0, stream>>>(hbuf, Bt2, al2, ar2, featb, el, er, resid, NNODES);
    agg1_kernel<<<NB4, 256, 0, stream>>>(featb, el, er, row_start, csr_src,
                                         resid, b2, out, NNODES);
}